// Round 9
// baseline (300.693 us; speedup 1.0000x reference)
//
#include <hip/hip_runtime.h>
#include <hip/hip_bf16.h>
#include <math.h>

static constexpr int DM = 1024;   // d_model
static constexpr int NH = 16;     // heads
static constexpr int DH = 64;     // head dim
static constexpr int QKV = 3 * DM;

typedef __attribute__((ext_vector_type(8))) short short8v;  // 8 bf16 = 4 VGPR
typedef __attribute__((ext_vector_type(4))) float f32x4;

__device__ inline short f2bf(float x) {
    __hip_bfloat16 h = __float2bfloat16(x);
    return *reinterpret_cast<short*>(&h);
}

// async global->LDS, 16B per lane. LDS dst must be wave-uniform (HW writes
// lane i at dst + i*16); global src is per-lane.
__device__ inline void gload16(const void* g, void* l) {
    __builtin_amdgcn_global_load_lds(
        (const __attribute__((address_space(1))) unsigned int*)g,
        (__attribute__((address_space(3))) unsigned int*)l, 16, 0, 0);
}

// ---------------------------------------------------------------------------
// Fused fp32 -> bf16 convert for all five inputs (one launch).
// ---------------------------------------------------------------------------
__global__ __launch_bounds__(256)
void convert_inputs(const float* __restrict__ x,  const float* __restrict__ wq,
                    const float* __restrict__ wk, const float* __restrict__ wv,
                    const float* __restrict__ wo, short* __restrict__ xh,
                    short* __restrict__ wqkv, short* __restrict__ woh,
                    int nx, int nw) {
    const int i = (blockIdx.x * 256 + threadIdx.x) * 4;
    const float* src;
    short* dst;
    int off;
    if (i < nx)                { src = x;  dst = xh;            off = i; }
    else if (i < nx + nw)      { src = wq; dst = wqkv;          off = i - nx; }
    else if (i < nx + 2 * nw)  { src = wk; dst = wqkv + nw;     off = i - nx - nw; }
    else if (i < nx + 3 * nw)  { src = wv; dst = wqkv + 2 * nw; off = i - nx - 2 * nw; }
    else if (i < nx + 4 * nw)  { src = wo; dst = woh;           off = i - nx - 3 * nw; }
    else return;
    const float4 v = *(const float4*)(src + off);
    short4 o;
    o.x = f2bf(v.x); o.y = f2bf(v.y); o.z = f2bf(v.z); o.w = f2bf(v.w);
    *(short4*)(dst + off) = o;
}

// ---------------------------------------------------------------------------
// bf16 MFMA GEMM, m97 structure (unchanged, passing).
// ---------------------------------------------------------------------------
template <int BF16OUT>
__global__ __launch_bounds__(256)
void gemm_bt_mfma(const short* __restrict__ A, const short* __restrict__ B,
                  void* __restrict__ Cv, int M, int N, int K) {
    __shared__ __align__(16) short As[128 * 32];
    __shared__ __align__(16) short Bs[128 * 32];
    const int tid = threadIdx.x;
    const int w = tid >> 6, l = tid & 63;
    const int lo = l & 15, hi = l >> 4;
    const int wr = w >> 1, wc = w & 1;
    const size_t m0 = (size_t)blockIdx.y * 128;
    const size_t n0 = (size_t)blockIdx.x * 128;

    const int cr = (w * 2) * 16 + (l >> 2);
    const int cc = (l & 3) * 8;
    const short* Ag0 = A + (m0 + cr) * K + cc;
    const short* Ag1 = Ag0 + (size_t)16 * K;
    const short* Bg0 = B + (n0 + cr) * K + cc;
    const short* Bg1 = Bg0 + (size_t)16 * K;
    short* As0 = As + (w * 2) * 512;
    short* As1 = As0 + 512;
    short* Bs0 = Bs + (w * 2) * 512;
    short* Bs1 = Bs0 + 512;

    f32x4 acc[4][4];
    #pragma unroll
    for (int mi = 0; mi < 4; ++mi)
        #pragma unroll
        for (int nj = 0; nj < 4; ++nj)
            acc[mi][nj] = (f32x4){0.f, 0.f, 0.f, 0.f};

    const int aoff = (wr * 64 + lo) * 32 + hi * 8;
    const int boff = (wc * 64 + lo) * 32 + hi * 8;

    for (int k0 = 0; k0 < K; k0 += 32) {
        __syncthreads();
        gload16(Ag0 + k0, As0);
        gload16(Ag1 + k0, As1);
        gload16(Bg0 + k0, Bs0);
        gload16(Bg1 + k0, Bs1);
        __syncthreads();
        short8v af[4], bf[4];
        #pragma unroll
        for (int mi = 0; mi < 4; ++mi)
            af[mi] = *(const short8v*)&As[aoff + mi * 16 * 32];
        #pragma unroll
        for (int nj = 0; nj < 4; ++nj)
            bf[nj] = *(const short8v*)&Bs[boff + nj * 16 * 32];
        #pragma unroll
        for (int mi = 0; mi < 4; ++mi)
            #pragma unroll
            for (int nj = 0; nj < 4; ++nj)
                acc[mi][nj] = __builtin_amdgcn_mfma_f32_16x16x32_bf16(
                    af[mi], bf[nj], acc[mi][nj], 0, 0, 0);
    }

    const size_t mbase = m0 + wr * 64 + hi * 4;
    const size_t nbase = n0 + wc * 64 + lo;
    #pragma unroll
    for (int mi = 0; mi < 4; ++mi)
        #pragma unroll
        for (int nj = 0; nj < 4; ++nj)
            #pragma unroll
            for (int rg = 0; rg < 4; ++rg) {
                const size_t m = mbase + mi * 16 + rg;
                const size_t n = nbase + nj * 16;
                if (BF16OUT)
                    ((short*)Cv)[m * N + n] = f2bf(acc[mi][nj][rg]);
                else
                    ((float*)Cv)[m * N + n] = acc[mi][nj][rg];
            }
}

// ---------------------------------------------------------------------------
// RoPE on bf16 QKV buffer (Q scaled by 1/8). (unchanged, passing)
// ---------------------------------------------------------------------------
__global__ __launch_bounds__(256)
void rope_bf16(const short* __restrict__ QKVr, const int* __restrict__ pos,
               short* __restrict__ Qh, short* __restrict__ Kh, int S, int rows) {
    int idx = blockIdx.x * 256 + threadIdx.x;
    const int per = rows * (DM / 2);
    bool isK = false;
    if (idx >= per) { idx -= per; isK = true; }
    if (idx >= per) return;
    const int row = idx >> 9;
    const int rem = idx & 511;
    const int h = rem >> 5, k = rem & 31;
    const unsigned pin = *(const unsigned*)(QKVr + (size_t)row * QKV +
                                            (isK ? DM : 0) + h * DH + 2 * k);
    const float x0 = __uint_as_float(pin << 16);
    const float x1 = __uint_as_float(pin & 0xffff0000u);
    const float ang = (float)pos[row % S] * powf(10000.0f, -(float)k * (1.0f / 32.0f));
    const float c = cosf(ang), sn = sinf(ang);
    float y0 = c * x0 - sn * x1;
    float y1 = sn * x0 + c * x1;
    if (!isK) { y0 *= 0.125f; y1 *= 0.125f; }
    const int b = row / S, sr = row % S;
    short* dst = (isK ? Kh : Qh) + ((size_t)(b * NH + h) * S + sr) * DH + 2 * k;
    *(unsigned*)dst = ((unsigned)(unsigned short)f2bf(y1) << 16)
                    | (unsigned short)f2bf(y0);
}

// ---------------------------------------------------------------------------
// V slice of QKV buffer -> per-head transposed Vt[B*H][64][S]. (unchanged)
// ---------------------------------------------------------------------------
__global__ __launch_bounds__(256)
void v_transpose_bf16(const short* __restrict__ QKVr, short* __restrict__ Vt, int S) {
    __shared__ __align__(16) short T[64][72];
    const int bh = blockIdx.y;
    const int b = bh / NH, h = bh - b * NH;
    const int s0 = blockIdx.x * 64;
    const int tid = threadIdx.x;
    const int r = tid >> 2, seg = (tid & 3) * 16;
    const short* src = QKVr + (size_t)(b * S + s0 + r) * QKV + 2 * DM + h * DH + seg;
    const short8v a0 = *(const short8v*)(src);
    const short8v a1 = *(const short8v*)(src + 8);
    #pragma unroll
    for (int j = 0; j < 8; ++j) T[seg + j][r] = a0[j];
    #pragma unroll
    for (int j = 0; j < 8; ++j) T[seg + 8 + j][r] = a1[j];
    __syncthreads();
    const uint4* sv = (const uint4*)&T[r][seg];
    uint4* dv = (uint4*)&Vt[((size_t)bh * DH + r) * S + s0 + seg];
    dv[0] = sv[0]; dv[1] = sv[1];
}

// ---------------------------------------------------------------------------
// MFMA flash attention, R9 = R8 KV-split with SPILL-FREE combine.
// Block = 512 thr = 8 waves = 4 pairs x 2 halves; half h does kv blocks
// kb = h, h+2, ... Loop phase identical to R7/R8. Combine phase rewritten
// with NO pointers/references into register arrays (rule #20): explicit
// macro-duplicated code per tile, constant indices only.
// ---------------------------------------------------------------------------
__global__ __launch_bounds__(512, 4)
void attn_mfma(const short* __restrict__ Qh, const short* __restrict__ Kh,
               const short* __restrict__ Vt, short* __restrict__ Oh, int S) {
    // P region: [8 waves][2 tiles][16][72] bf16 = 36864 B (loop phase).
    // Merge region: [4 pairs][2 tiles][64 lanes][24] f32 = 49152 B (aliases
    // P after the first combine barrier).
    __shared__ __align__(16) char smem[49152];
    auto P = (__hip_bfloat16 (*)[2][16][72])smem;
    float* MB = (float*)smem;

    const int b = blockIdx.z, h = blockIdx.y;
    const int bh = b * NH + h;
    const int tid = threadIdx.x;
    const int w = tid >> 6, l = tid & 63;
    const int pw = w >> 1, half = w & 1;
    const int lo = l & 15, hi = l >> 4;
    const int T = S >> 4;
    const int p = blockIdx.x * 4 + pw;
    const int q0B = (T - 1 - p) << 4;
    const int q0F = p << 4;
    const int nkbB = (q0B + 79) >> 6;
    const int nkbF = (q0F + 79) >> 6;

    const short* Qp = Qh + (size_t)bh * S * DH;
    const short* Kp = Kh + (size_t)bh * S * DH;
    const short* Vp = Vt + (size_t)bh * DH * S;

    const short8v qB0 = *(const short8v*)(Qp + (size_t)(q0B + lo) * DH + hi * 8);
    const short8v qB1 = *(const short8v*)(Qp + (size_t)(q0B + lo) * DH + 32 + hi * 8);
    const short8v qF0 = *(const short8v*)(Qp + (size_t)(q0F + lo) * DH + hi * 8);
    const short8v qF1 = *(const short8v*)(Qp + (size_t)(q0F + lo) * DH + 32 + hi * 8);

    short8v ones;
    #pragma unroll
    for (int i = 0; i < 8; ++i) ones[i] = (short)0x3F80;   // bf16 1.0

    f32x4 oB[4], oF[4];
    f32x4 laB = (f32x4){0.f, 0.f, 0.f, 0.f};
    f32x4 laF = (f32x4){0.f, 0.f, 0.f, 0.f};
    float mB[4], mF[4];
    #pragma unroll
    for (int i = 0; i < 4; ++i) {
        oB[i] = (f32x4){0.f, 0.f, 0.f, 0.f};
        oF[i] = (f32x4){0.f, 0.f, 0.f, 0.f};
        mB[i] = -INFINITY; mF[i] = -INFINITY;
    }
    const f32x4 z = (f32x4){0.f, 0.f, 0.f, 0.f};
    const float THR = 8.0f;

    auto softmaxTile = [&](f32x4 (&s)[4], f32x4 (&o)[4], f32x4& la,
                           float (&m)[4], bool masked, int q0, int kvb, int tsel) {
        float sv[4][4], pmax[4];
        #pragma unroll
        for (int rg = 0; rg < 4; ++rg) {
            #pragma unroll
            for (int kt = 0; kt < 4; ++kt) {
                float v = s[kt][rg];
                if (masked && (kvb + kt * 16 + lo > q0 + hi * 4 + rg)) v = -INFINITY;
                sv[rg][kt] = v;
            }
            pmax[rg] = fmaxf(fmaxf(sv[rg][0], sv[rg][1]),
                             fmaxf(sv[rg][2], sv[rg][3]));
        }
        int need = 0;
        #pragma unroll
        for (int rg = 0; rg < 4; ++rg) need |= (pmax[rg] > m[rg] + THR);
        if (__any(need)) {
            #pragma unroll
            for (int rg = 0; rg < 4; ++rg) {
                float bm = pmax[rg];
                bm = fmaxf(bm, __shfl_xor(bm, 1));
                bm = fmaxf(bm, __shfl_xor(bm, 2));
                bm = fmaxf(bm, __shfl_xor(bm, 4));
                bm = fmaxf(bm, __shfl_xor(bm, 8));
                const float mn = fmaxf(m[rg], bm);
                const float c = __expf(m[rg] - mn);
                m[rg] = mn;
                la[rg] *= c;
                #pragma unroll
                for (int dt = 0; dt < 4; ++dt) o[dt][rg] *= c;
            }
        }
        #pragma unroll
        for (int rg = 0; rg < 4; ++rg)
            #pragma unroll
            for (int kt = 0; kt < 4; ++kt)
                P[w][tsel][hi * 4 + rg][kt * 16 + lo] =
                    __float2bfloat16(__expf(sv[rg][kt] - m[rg]));
    };

    for (int kb = half; kb < nkbB; kb += 2) {
        const int kvb = kb * 64;
        const bool actF = kb < nkbF;

        short8v kf0[4], kf1[4];
        #pragma unroll
        for (int kt = 0; kt < 4; ++kt) {
            const short* kbase = Kp + (size_t)(kvb + kt * 16 + lo) * DH + hi * 8;
            kf0[kt] = *(const short8v*)(kbase);
            kf1[kt] = *(const short8v*)(kbase + 32);
        }
        short8v vf0[4], vf1[4];
        #pragma unroll
        for (int dt = 0; dt < 4; ++dt) {
            const short* vbase = Vp + (size_t)(dt * 16 + lo) * S + kvb + hi * 8;
            vf0[dt] = *(const short8v*)(vbase);
            vf1[dt] = *(const short8v*)(vbase + 32);
        }

        f32x4 sB[4], sF[4];
        #pragma unroll
        for (int kt = 0; kt < 4; ++kt) {
            f32x4 a = z;
            a = __builtin_amdgcn_mfma_f32_16x16x32_bf16(qB0, kf0[kt], a, 0, 0, 0);
            a = __builtin_amdgcn_mfma_f32_16x16x32_bf16(qB1, kf1[kt], a, 0, 0, 0);
            sB[kt] = a;
        }
        if (actF) {
            #pragma unroll
            for (int kt = 0; kt < 4; ++kt) {
                f32x4 a = z;
                a = __builtin_amdgcn_mfma_f32_16x16x32_bf16(qF0, kf0[kt], a, 0, 0, 0);
                a = __builtin_amdgcn_mfma_f32_16x16x32_bf16(qF1, kf1[kt], a, 0, 0, 0);
                sF[kt] = a;
            }
        }

        softmaxTile(sB, oB, laB, mB, kb == nkbB - 1, q0B, kvb, 0);
        if (actF) softmaxTile(sF, oF, laF, mF, kb == nkbF - 1, q0F, kvb, 1);

        asm volatile("s_waitcnt lgkmcnt(0)" ::: "memory");
        const short8v paB0 = *(const short8v*)&P[w][0][lo][hi * 8];
        const short8v paB1 = *(const short8v*)&P[w][0][lo][32 + hi * 8];
        const short8v paF0 = *(const short8v*)&P[w][1][lo][hi * 8];
        const short8v paF1 = *(const short8v*)&P[w][1][lo][32 + hi * 8];

        laB = __builtin_amdgcn_mfma_f32_16x16x32_bf16(paB0, ones, laB, 0, 0, 0);
        laB = __builtin_amdgcn_mfma_f32_16x16x32_bf16(paB1, ones, laB, 0, 0, 0);
        if (actF) {
            laF = __builtin_amdgcn_mfma_f32_16x16x32_bf16(paF0, ones, laF, 0, 0, 0);
            laF = __builtin_amdgcn_mfma_f32_16x16x32_bf16(paF1, ones, laF, 0, 0, 0);
        }

        #pragma unroll
        for (int dt = 0; dt < 4; ++dt) {
            oB[dt] = __builtin_amdgcn_mfma_f32_16x16x32_bf16(paB0, vf0[dt], oB[dt], 0, 0, 0);
            oB[dt] = __builtin_amdgcn_mfma_f32_16x16x32_bf16(paB1, vf1[dt], oB[dt], 0, 0, 0);
            if (actF) {
                oF[dt] = __builtin_amdgcn_mfma_f32_16x16x32_bf16(paF0, vf0[dt], oF[dt], 0, 0, 0);
                oF[dt] = __builtin_amdgcn_mfma_f32_16x16x32_bf16(paF1, vf1[dt], oF[dt], 0, 0, 0);
            }
        }
    }

    // ---- KV-split combine (spill-free: no pointers into register arrays) ----
    __syncthreads();                 // all loops done; P region now dead

#define STORE_HALF(TIDX, OT, MT, LAT)                                      \
    do {                                                                   \
        f32x4* dst = (f32x4*)(MB + (size_t)((pw * 2 + (TIDX)) * 64 + l) * 24); \
        dst[0] = OT[0]; dst[1] = OT[1]; dst[2] = OT[2]; dst[3] = OT[3];    \
        dst[4] = (f32x4){MT[0], MT[1], MT[2], MT[3]};                      \
        dst[5] = LAT;                                                      \
    } while (0)

#define MERGE_HALF(TIDX, OT, MT, LAT, Q0T)                                 \
    do {                                                                   \
        const f32x4* src = (const f32x4*)(MB + (size_t)((pw * 2 + (TIDX)) * 64 + l) * 24); \
        const f32x4 o1_0 = src[0], o1_1 = src[1], o1_2 = src[2], o1_3 = src[3]; \
        const f32x4 m1 = src[4];                                           \
        const f32x4 la1 = src[5];                                          \
        short* Op = Oh + (size_t)(b * S + (Q0T)) * DM + h * DH;            \
        _Pragma("unroll")                                                  \
        for (int rg = 0; rg < 4; ++rg) {                                   \
            const float mst = fmaxf(MT[rg], m1[rg]);                       \
            const float c0 = __expf(MT[rg] - mst);                         \
            const float c1 = __expf(m1[rg] - mst);                         \
            const float iv = 1.0f / (LAT[rg] * c0 + la1[rg] * c1);         \
            Op[(size_t)(hi * 4 + rg) * DM +  0 + lo] = f2bf((OT[0][rg] * c0 + o1_0[rg] * c1) * iv); \
            Op[(size_t)(hi * 4 + rg) * DM + 16 + lo] = f2bf((OT[1][rg] * c0 + o1_1[rg] * c1) * iv); \
            Op[(size_t)(hi * 4 + rg) * DM + 32 + lo] = f2bf((OT[2][rg] * c0 + o1_2[rg] * c1) * iv); \
            Op[(size_t)(hi * 4 + rg) * DM + 48 + lo] = f2bf((OT[3][rg] * c0 + o1_3[rg] * c1) * iv); \
        }                                                                  \
    } while (0)

    if (half == 1) {
        STORE_HALF(0, oB, mB, laB);
        STORE_HALF(1, oF, mF, laF);
    }
    __syncthreads();
    if (half == 0) {
        MERGE_HALF(0, oB, mB, laB, q0B);
        MERGE_HALF(1, oF, mF, laF, q0F);
    }
#undef STORE_HALF
#undef MERGE_HALF
}

// ---------------------------------------------------------------------------
extern "C" void kernel_launch(void* const* d_in, const int* in_sizes, int n_in,
                              void* d_out, int out_size, void* d_ws, size_t ws_size,
                              hipStream_t stream) {
    const float* x  = (const float*)d_in[0];
    const int*  pos = (const int*)d_in[1];
    const float* wq = (const float*)d_in[2];
    const float* wk = (const float*)d_in[3];
    const float* wv = (const float*)d_in[4];
    const float* wo = (const float*)d_in[5];
    float* out = (float*)d_out;

    const int S = in_sizes[1];              // 2048
    const int rows = in_sizes[0] / DM;      // B*S
    const int Bb = rows / S;

    short* xh   = (short*)d_ws;
    short* wqkv = xh + (size_t)rows * DM;
    short* woh  = wqkv + (size_t)QKV * DM;
    short* QKVr = woh + (size_t)DM * DM;
    short* Qh   = QKVr + (size_t)rows * QKV;
    short* Kh   = Qh + (size_t)rows * DM;
    short* Vt   = Kh + (size_t)rows * DM;
    short* Oh   = Vt + (size_t)rows * DM;

    const int nx = rows * DM;
    const int nw = DM * DM;
    const int ntot = nx + 4 * nw;
    convert_inputs<<<(ntot / 4 + 255) / 256, 256, 0, stream>>>(
        x, wq, wk, wv, wo, xh, wqkv, woh, nx, nw);

    gemm_bt_mfma<1><<<dim3(QKV / 128, rows / 128), 256, 0, stream>>>(
        xh, wqkv, QKVr, rows, QKV, DM);

    const int total = 2 * rows * (DM / 2);
    rope_bf16<<<(total + 255) / 256, 256, 0, stream>>>(QKVr, pos, Qh, Kh, S, rows);
    v_transpose_bf16<<<dim3(S / 64, Bb * NH), 256, 0, stream>>>(QKVr, Vt, S);

    attn_mfma<<<dim3(S / 128, NH, Bb), 512, 0, stream>>>(Qh, Kh, Vt, Oh, S);

    gemm_bt_mfma<0><<<dim3(DM / 128, rows / 128), 256, 0, stream>>>(
        Oh, woh, out, rows, DM, DM);
}

// Round 10
// 226.834 us; speedup vs baseline: 1.3256x; 1.3256x over previous
//
#include <hip/hip_runtime.h>
#include <hip/hip_bf16.h>
#include <math.h>

static constexpr int DM = 1024;   // d_model
static constexpr int NH = 16;     // heads
static constexpr int DH = 64;     // head dim
static constexpr int QKV = 3 * DM;

typedef __attribute__((ext_vector_type(8))) short short8v;  // 8 bf16 = 4 VGPR
typedef __attribute__((ext_vector_type(4))) float f32x4;

__device__ inline short f2bf(float x) {
    __hip_bfloat16 h = __float2bfloat16(x);
    return *reinterpret_cast<short*>(&h);
}

// async global->LDS, 16B per lane. LDS dst must be wave-uniform (HW writes
// lane i at dst + i*16); global src is per-lane.
__device__ inline void gload16(const void* g, void* l) {
    __builtin_amdgcn_global_load_lds(
        (const __attribute__((address_space(1))) unsigned int*)g,
        (__attribute__((address_space(3))) unsigned int*)l, 16, 0, 0);
}

// ---------------------------------------------------------------------------
// Fused fp32 -> bf16 convert for all five inputs (one launch).
// ---------------------------------------------------------------------------
__global__ __launch_bounds__(256)
void convert_inputs(const float* __restrict__ x,  const float* __restrict__ wq,
                    const float* __restrict__ wk, const float* __restrict__ wv,
                    const float* __restrict__ wo, short* __restrict__ xh,
                    short* __restrict__ wqkv, short* __restrict__ woh,
                    int nx, int nw) {
    const int i = (blockIdx.x * 256 + threadIdx.x) * 4;
    const float* src;
    short* dst;
    int off;
    if (i < nx)                { src = x;  dst = xh;            off = i; }
    else if (i < nx + nw)      { src = wq; dst = wqkv;          off = i - nx; }
    else if (i < nx + 2 * nw)  { src = wk; dst = wqkv + nw;     off = i - nx - nw; }
    else if (i < nx + 3 * nw)  { src = wv; dst = wqkv + 2 * nw; off = i - nx - 2 * nw; }
    else if (i < nx + 4 * nw)  { src = wo; dst = woh;           off = i - nx - 3 * nw; }
    else return;
    const float4 v = *(const float4*)(src + off);
    short4 o;
    o.x = f2bf(v.x); o.y = f2bf(v.y); o.z = f2bf(v.z); o.w = f2bf(v.w);
    *(short4*)(dst + off) = o;
}

// ---------------------------------------------------------------------------
// bf16 MFMA GEMM, m97 structure (unchanged, passing).
// ---------------------------------------------------------------------------
template <int BF16OUT>
__global__ __launch_bounds__(256)
void gemm_bt_mfma(const short* __restrict__ A, const short* __restrict__ B,
                  void* __restrict__ Cv, int M, int N, int K) {
    __shared__ __align__(16) short As[128 * 32];
    __shared__ __align__(16) short Bs[128 * 32];
    const int tid = threadIdx.x;
    const int w = tid >> 6, l = tid & 63;
    const int lo = l & 15, hi = l >> 4;
    const int wr = w >> 1, wc = w & 1;
    const size_t m0 = (size_t)blockIdx.y * 128;
    const size_t n0 = (size_t)blockIdx.x * 128;

    const int cr = (w * 2) * 16 + (l >> 2);
    const int cc = (l & 3) * 8;
    const short* Ag0 = A + (m0 + cr) * K + cc;
    const short* Ag1 = Ag0 + (size_t)16 * K;
    const short* Bg0 = B + (n0 + cr) * K + cc;
    const short* Bg1 = Bg0 + (size_t)16 * K;
    short* As0 = As + (w * 2) * 512;
    short* As1 = As0 + 512;
    short* Bs0 = Bs + (w * 2) * 512;
    short* Bs1 = Bs0 + 512;

    f32x4 acc[4][4];
    #pragma unroll
    for (int mi = 0; mi < 4; ++mi)
        #pragma unroll
        for (int nj = 0; nj < 4; ++nj)
            acc[mi][nj] = (f32x4){0.f, 0.f, 0.f, 0.f};

    const int aoff = (wr * 64 + lo) * 32 + hi * 8;
    const int boff = (wc * 64 + lo) * 32 + hi * 8;

    for (int k0 = 0; k0 < K; k0 += 32) {
        __syncthreads();
        gload16(Ag0 + k0, As0);
        gload16(Ag1 + k0, As1);
        gload16(Bg0 + k0, Bs0);
        gload16(Bg1 + k0, Bs1);
        __syncthreads();
        short8v af[4], bf[4];
        #pragma unroll
        for (int mi = 0; mi < 4; ++mi)
            af[mi] = *(const short8v*)&As[aoff + mi * 16 * 32];
        #pragma unroll
        for (int nj = 0; nj < 4; ++nj)
            bf[nj] = *(const short8v*)&Bs[boff + nj * 16 * 32];
        #pragma unroll
        for (int mi = 0; mi < 4; ++mi)
            #pragma unroll
            for (int nj = 0; nj < 4; ++nj)
                acc[mi][nj] = __builtin_amdgcn_mfma_f32_16x16x32_bf16(
                    af[mi], bf[nj], acc[mi][nj], 0, 0, 0);
    }

    const size_t mbase = m0 + wr * 64 + hi * 4;
    const size_t nbase = n0 + wc * 64 + lo;
    #pragma unroll
    for (int mi = 0; mi < 4; ++mi)
        #pragma unroll
        for (int nj = 0; nj < 4; ++nj)
            #pragma unroll
            for (int rg = 0; rg < 4; ++rg) {
                const size_t m = mbase + mi * 16 + rg;
                const size_t n = nbase + nj * 16;
                if (BF16OUT)
                    ((short*)Cv)[m * N + n] = f2bf(acc[mi][nj][rg]);
                else
                    ((float*)Cv)[m * N + n] = acc[mi][nj][rg];
            }
}

// ---------------------------------------------------------------------------
// RoPE on bf16 QKV buffer (Q scaled by 1/8). (unchanged, passing)
// ---------------------------------------------------------------------------
__global__ __launch_bounds__(256)
void rope_bf16(const short* __restrict__ QKVr, const int* __restrict__ pos,
               short* __restrict__ Qh, short* __restrict__ Kh, int S, int rows) {
    int idx = blockIdx.x * 256 + threadIdx.x;
    const int per = rows * (DM / 2);
    bool isK = false;
    if (idx >= per) { idx -= per; isK = true; }
    if (idx >= per) return;
    const int row = idx >> 9;
    const int rem = idx & 511;
    const int h = rem >> 5, k = rem & 31;
    const unsigned pin = *(const unsigned*)(QKVr + (size_t)row * QKV +
                                            (isK ? DM : 0) + h * DH + 2 * k);
    const float x0 = __uint_as_float(pin << 16);
    const float x1 = __uint_as_float(pin & 0xffff0000u);
    const float ang = (float)pos[row % S] * powf(10000.0f, -(float)k * (1.0f / 32.0f));
    const float c = cosf(ang), sn = sinf(ang);
    float y0 = c * x0 - sn * x1;
    float y1 = sn * x0 + c * x1;
    if (!isK) { y0 *= 0.125f; y1 *= 0.125f; }
    const int b = row / S, sr = row % S;
    short* dst = (isK ? Kh : Qh) + ((size_t)(b * NH + h) * S + sr) * DH + 2 * k;
    *(unsigned*)dst = ((unsigned)(unsigned short)f2bf(y1) << 16)
                    | (unsigned short)f2bf(y0);
}

// ---------------------------------------------------------------------------
// V slice of QKV buffer -> per-head transposed Vt[B*H][64][S]. (unchanged)
// ---------------------------------------------------------------------------
__global__ __launch_bounds__(256)
void v_transpose_bf16(const short* __restrict__ QKVr, short* __restrict__ Vt, int S) {
    __shared__ __align__(16) short T[64][72];
    const int bh = blockIdx.y;
    const int b = bh / NH, h = bh - b * NH;
    const int s0 = blockIdx.x * 64;
    const int tid = threadIdx.x;
    const int r = tid >> 2, seg = (tid & 3) * 16;
    const short* src = QKVr + (size_t)(b * S + s0 + r) * QKV + 2 * DM + h * DH + seg;
    const short8v a0 = *(const short8v*)(src);
    const short8v a1 = *(const short8v*)(src + 8);
    #pragma unroll
    for (int j = 0; j < 8; ++j) T[seg + j][r] = a0[j];
    #pragma unroll
    for (int j = 0; j < 8; ++j) T[seg + 8 + j][r] = a1[j];
    __syncthreads();
    const uint4* sv = (const uint4*)&T[r][seg];
    uint4* dv = (uint4*)&Vt[((size_t)bh * DH + r) * S + s0 + seg];
    dv[0] = sv[0]; dv[1] = sv[1];
}

// ---------------------------------------------------------------------------
// MFMA flash attention, R10 = KV-split with PHASE-SEQUENTIAL pair.
// Block = 512 thr = 8 waves = 4 pairs x 2 halves. Two phases: tile B
// (=T-1-p) then tile F (=p). In each phase, half h processes kv-blocks
// kb = h, h+2, ...; then block barrier; half 1 stores (o,m,la) to MB;
// barrier; half 0 merges (exact fp32 flash combine) and writes output.
// Only ONE tile's state is live at a time (~100 VGPR -> fits the 128-VGPR
// cap for 2 blocks/CU = 16 waves/CU). launch_bounds(512,2): under the
// empirically-observed blocks/CU semantics (R8/R9: (512,4) -> 64-VGPR cap)
// this targets 2 blocks/CU -> 128 VGPR.
// ---------------------------------------------------------------------------
__global__ __launch_bounds__(512, 2)
void attn_mfma(const short* __restrict__ Qh, const short* __restrict__ Kh,
               const short* __restrict__ Vt, short* __restrict__ Oh, int S) {
    __shared__ __align__(16) __hip_bfloat16 P[8][16][72];   // 18432 B, per-wave
    __shared__ __align__(16) float MB[4][64][24];           // 24576 B, combine

    const int b = blockIdx.z, h = blockIdx.y;
    const int bh = b * NH + h;
    const int tid = threadIdx.x;
    const int w = tid >> 6, l = tid & 63;
    const int pw = w >> 1, half = w & 1;
    const int lo = l & 15, hi = l >> 4;
    const int T = S >> 4;
    const int p = blockIdx.x * 4 + pw;

    const short* Qp = Qh + (size_t)bh * S * DH;
    const short* Kp = Kh + (size_t)bh * S * DH;
    const short* Vp = Vt + (size_t)bh * DH * S;

    short8v ones;
    #pragma unroll
    for (int i = 0; i < 8; ++i) ones[i] = (short)0x3F80;   // bf16 1.0

    const f32x4 z = (f32x4){0.f, 0.f, 0.f, 0.f};
    const float THR = 8.0f;

    for (int t = 0; t < 2; ++t) {
        const int q0 = ((t == 0) ? (T - 1 - p) : p) << 4;
        const int nkb = (q0 + 79) >> 6;

        const short8v qf0 = *(const short8v*)(Qp + (size_t)(q0 + lo) * DH + hi * 8);
        const short8v qf1 = *(const short8v*)(Qp + (size_t)(q0 + lo) * DH + 32 + hi * 8);

        f32x4 o[4];
        f32x4 la = z;
        float m[4];
        #pragma unroll
        for (int i = 0; i < 4; ++i) {
            o[i] = z;
            m[i] = -INFINITY;
        }

        for (int kb = half; kb < nkb; kb += 2) {
            const int kvb = kb * 64;

            // ---- K fragments + QK^T
            f32x4 s[4];
            #pragma unroll
            for (int kt = 0; kt < 4; ++kt) {
                const short* kbase = Kp + (size_t)(kvb + kt * 16 + lo) * DH + hi * 8;
                const short8v kf0 = *(const short8v*)(kbase);
                const short8v kf1 = *(const short8v*)(kbase + 32);
                f32x4 a = z;
                a = __builtin_amdgcn_mfma_f32_16x16x32_bf16(qf0, kf0, a, 0, 0, 0);
                a = __builtin_amdgcn_mfma_f32_16x16x32_bf16(qf1, kf1, a, 0, 0, 0);
                s[kt] = a;
            }

            // ---- softmax (defer-max), mask only on the tile's last block
            const bool masked = (kb == nkb - 1);
            float sv[4][4], pmax[4];
            #pragma unroll
            for (int rg = 0; rg < 4; ++rg) {
                #pragma unroll
                for (int kt = 0; kt < 4; ++kt) {
                    float v = s[kt][rg];
                    if (masked && (kvb + kt * 16 + lo > q0 + hi * 4 + rg)) v = -INFINITY;
                    sv[rg][kt] = v;
                }
                pmax[rg] = fmaxf(fmaxf(sv[rg][0], sv[rg][1]),
                                 fmaxf(sv[rg][2], sv[rg][3]));
            }
            int need = 0;
            #pragma unroll
            for (int rg = 0; rg < 4; ++rg) need |= (pmax[rg] > m[rg] + THR);
            if (__any(need)) {
                #pragma unroll
                for (int rg = 0; rg < 4; ++rg) {
                    float bm = pmax[rg];
                    bm = fmaxf(bm, __shfl_xor(bm, 1));
                    bm = fmaxf(bm, __shfl_xor(bm, 2));
                    bm = fmaxf(bm, __shfl_xor(bm, 4));
                    bm = fmaxf(bm, __shfl_xor(bm, 8));
                    const float mn = fmaxf(m[rg], bm);
                    const float c = __expf(m[rg] - mn);
                    m[rg] = mn;
                    la[rg] *= c;
                    #pragma unroll
                    for (int dt = 0; dt < 4; ++dt) o[dt][rg] *= c;
                }
            }
            #pragma unroll
            for (int rg = 0; rg < 4; ++rg)
                #pragma unroll
                for (int kt = 0; kt < 4; ++kt)
                    P[w][hi * 4 + rg][kt * 16 + lo] =
                        __float2bfloat16(__expf(sv[rg][kt] - m[rg]));

            asm volatile("s_waitcnt lgkmcnt(0)" ::: "memory");
            const short8v pa0 = *(const short8v*)&P[w][lo][hi * 8];
            const short8v pa1 = *(const short8v*)&P[w][lo][32 + hi * 8];

            // ---- row-sum via MFMA
            la = __builtin_amdgcn_mfma_f32_16x16x32_bf16(pa0, ones, la, 0, 0, 0);
            la = __builtin_amdgcn_mfma_f32_16x16x32_bf16(pa1, ones, la, 0, 0, 0);

            // ---- V fragments + PV
            #pragma unroll
            for (int dt = 0; dt < 4; ++dt) {
                const short* vbase = Vp + (size_t)(dt * 16 + lo) * S + kvb + hi * 8;
                const short8v vf0 = *(const short8v*)(vbase);
                const short8v vf1 = *(const short8v*)(vbase + 32);
                o[dt] = __builtin_amdgcn_mfma_f32_16x16x32_bf16(pa0, vf0, o[dt], 0, 0, 0);
                o[dt] = __builtin_amdgcn_mfma_f32_16x16x32_bf16(pa1, vf1, o[dt], 0, 0, 0);
            }
        }

        // ---- KV-split combine for this phase ----
        __syncthreads();
        if (half == 1) {
            f32x4* dst = (f32x4*)&MB[pw][l][0];
            dst[0] = o[0]; dst[1] = o[1]; dst[2] = o[2]; dst[3] = o[3];
            dst[4] = (f32x4){m[0], m[1], m[2], m[3]};
            dst[5] = la;
        }
        __syncthreads();
        if (half == 0) {
            const f32x4* src = (const f32x4*)&MB[pw][l][0];
            const f32x4 o1_0 = src[0], o1_1 = src[1], o1_2 = src[2], o1_3 = src[3];
            const f32x4 m1 = src[4];
            const f32x4 la1 = src[5];
            short* Op = Oh + (size_t)(b * S + q0) * DM + h * DH;
            #pragma unroll
            for (int rg = 0; rg < 4; ++rg) {
                const float mst = fmaxf(m[rg], m1[rg]);
                const float c0 = __expf(m[rg] - mst);
                const float c1 = __expf(m1[rg] - mst);
                const float iv = 1.0f / (la[rg] * c0 + la1[rg] * c1);
                Op[(size_t)(hi * 4 + rg) * DM +  0 + lo] =
                    f2bf((o[0][rg] * c0 + o1_0[rg] * c1) * iv);
                Op[(size_t)(hi * 4 + rg) * DM + 16 + lo] =
                    f2bf((o[1][rg] * c0 + o1_1[rg] * c1) * iv);
                Op[(size_t)(hi * 4 + rg) * DM + 32 + lo] =
                    f2bf((o[2][rg] * c0 + o1_2[rg] * c1) * iv);
                Op[(size_t)(hi * 4 + rg) * DM + 48 + lo] =
                    f2bf((o[3][rg] * c0 + o1_3[rg] * c1) * iv);
            }
        }
        // No extra barrier: next phase's MB store is behind the next phase's
        // first __syncthreads(), which orders it after this phase's MB reads.
    }
}

// ---------------------------------------------------------------------------
extern "C" void kernel_launch(void* const* d_in, const int* in_sizes, int n_in,
                              void* d_out, int out_size, void* d_ws, size_t ws_size,
                              hipStream_t stream) {
    const float* x  = (const float*)d_in[0];
    const int*  pos = (const int*)d_in[1];
    const float* wq = (const float*)d_in[2];
    const float* wk = (const float*)d_in[3];
    const float* wv = (const float*)d_in[4];
    const float* wo = (const float*)d_in[5];
    float* out = (float*)d_out;

    const int S = in_sizes[1];              // 2048
    const int rows = in_sizes[0] / DM;      // B*S
    const int Bb = rows / S;

    short* xh   = (short*)d_ws;
    short* wqkv = xh + (size_t)rows * DM;
    short* woh  = wqkv + (size_t)QKV * DM;
    short* QKVr = woh + (size_t)DM * DM;
    short* Qh   = QKVr + (size_t)rows * QKV;
    short* Kh   = Qh + (size_t)rows * DM;
    short* Vt   = Kh + (size_t)rows * DM;
    short* Oh   = Vt + (size_t)rows * DM;

    const int nx = rows * DM;
    const int nw = DM * DM;
    const int ntot = nx + 4 * nw;
    convert_inputs<<<(ntot / 4 + 255) / 256, 256, 0, stream>>>(
        x, wq, wk, wv, wo, xh, wqkv, woh, nx, nw);

    gemm_bt_mfma<1><<<dim3(QKV / 128, rows / 128), 256, 0, stream>>>(
        xh, wqkv, QKVr, rows, QKV, DM);

    const int total = 2 * rows * (DM / 2);
    rope_bf16<<<(total + 255) / 256, 256, 0, stream>>>(QKVr, pos, Qh, Kh, S, rows);
    v_transpose_bf16<<<dim3(S / 64, Bb * NH), 256, 0, stream>>>(QKVr, Vt, S);

    attn_mfma<<<dim3(S / 128, NH, Bb), 512, 0, stream>>>(Qh, Kh, Vt, Oh, S);

    gemm_bt_mfma<0><<<dim3(DM / 128, rows / 128), 256, 0, stream>>>(
        Oh, woh, out, rows, DM, DM);
}

// Round 11
// 208.910 us; speedup vs baseline: 1.4393x; 1.0858x over previous
//
#include <hip/hip_runtime.h>
#include <hip/hip_bf16.h>
#include <math.h>

static constexpr int DM = 1024;   // d_model
static constexpr int NH = 16;     // heads
static constexpr int DH = 64;     // head dim
static constexpr int QKV = 3 * DM;

typedef __attribute__((ext_vector_type(8))) short short8v;  // 8 bf16 = 4 VGPR
typedef __attribute__((ext_vector_type(4))) float f32x4;

__device__ inline short f2bf(float x) {
    __hip_bfloat16 h = __float2bfloat16(x);
    return *reinterpret_cast<short*>(&h);
}

// async global->LDS, 16B per lane. LDS dst must be wave-uniform (HW writes
// lane i at dst + i*16); global src is per-lane.
__device__ inline void gload16(const void* g, void* l) {
    __builtin_amdgcn_global_load_lds(
        (const __attribute__((address_space(1))) unsigned int*)g,
        (__attribute__((address_space(3))) unsigned int*)l, 16, 0, 0);
}

// ---------------------------------------------------------------------------
// Fused fp32 -> bf16 convert for all five inputs (one launch).
// ---------------------------------------------------------------------------
__global__ __launch_bounds__(256)
void convert_inputs(const float* __restrict__ x,  const float* __restrict__ wq,
                    const float* __restrict__ wk, const float* __restrict__ wv,
                    const float* __restrict__ wo, short* __restrict__ xh,
                    short* __restrict__ wqkv, short* __restrict__ woh,
                    int nx, int nw) {
    const int i = (blockIdx.x * 256 + threadIdx.x) * 4;
    const float* src;
    short* dst;
    int off;
    if (i < nx)                { src = x;  dst = xh;            off = i; }
    else if (i < nx + nw)      { src = wq; dst = wqkv;          off = i - nx; }
    else if (i < nx + 2 * nw)  { src = wk; dst = wqkv + nw;     off = i - nx - nw; }
    else if (i < nx + 3 * nw)  { src = wv; dst = wqkv + 2 * nw; off = i - nx - 2 * nw; }
    else if (i < nx + 4 * nw)  { src = wo; dst = woh;           off = i - nx - 3 * nw; }
    else return;
    const float4 v = *(const float4*)(src + off);
    short4 o;
    o.x = f2bf(v.x); o.y = f2bf(v.y); o.z = f2bf(v.z); o.w = f2bf(v.w);
    *(short4*)(dst + off) = o;
}

// ---------------------------------------------------------------------------
// bf16 MFMA GEMM, m97 structure (unchanged, passing).
// ---------------------------------------------------------------------------
template <int BF16OUT>
__global__ __launch_bounds__(256)
void gemm_bt_mfma(const short* __restrict__ A, const short* __restrict__ B,
                  void* __restrict__ Cv, int M, int N, int K) {
    __shared__ __align__(16) short As[128 * 32];
    __shared__ __align__(16) short Bs[128 * 32];
    const int tid = threadIdx.x;
    const int w = tid >> 6, l = tid & 63;
    const int lo = l & 15, hi = l >> 4;
    const int wr = w >> 1, wc = w & 1;
    const size_t m0 = (size_t)blockIdx.y * 128;
    const size_t n0 = (size_t)blockIdx.x * 128;

    const int cr = (w * 2) * 16 + (l >> 2);
    const int cc = (l & 3) * 8;
    const short* Ag0 = A + (m0 + cr) * K + cc;
    const short* Ag1 = Ag0 + (size_t)16 * K;
    const short* Bg0 = B + (n0 + cr) * K + cc;
    const short* Bg1 = Bg0 + (size_t)16 * K;
    short* As0 = As + (w * 2) * 512;
    short* As1 = As0 + 512;
    short* Bs0 = Bs + (w * 2) * 512;
    short* Bs1 = Bs0 + 512;

    f32x4 acc[4][4];
    #pragma unroll
    for (int mi = 0; mi < 4; ++mi)
        #pragma unroll
        for (int nj = 0; nj < 4; ++nj)
            acc[mi][nj] = (f32x4){0.f, 0.f, 0.f, 0.f};

    const int aoff = (wr * 64 + lo) * 32 + hi * 8;
    const int boff = (wc * 64 + lo) * 32 + hi * 8;

    for (int k0 = 0; k0 < K; k0 += 32) {
        __syncthreads();
        gload16(Ag0 + k0, As0);
        gload16(Ag1 + k0, As1);
        gload16(Bg0 + k0, Bs0);
        gload16(Bg1 + k0, Bs1);
        __syncthreads();
        short8v af[4], bf[4];
        #pragma unroll
        for (int mi = 0; mi < 4; ++mi)
            af[mi] = *(const short8v*)&As[aoff + mi * 16 * 32];
        #pragma unroll
        for (int nj = 0; nj < 4; ++nj)
            bf[nj] = *(const short8v*)&Bs[boff + nj * 16 * 32];
        #pragma unroll
        for (int mi = 0; mi < 4; ++mi)
            #pragma unroll
            for (int nj = 0; nj < 4; ++nj)
                acc[mi][nj] = __builtin_amdgcn_mfma_f32_16x16x32_bf16(
                    af[mi], bf[nj], acc[mi][nj], 0, 0, 0);
    }

    const size_t mbase = m0 + wr * 64 + hi * 4;
    const size_t nbase = n0 + wc * 64 + lo;
    #pragma unroll
    for (int mi = 0; mi < 4; ++mi)
        #pragma unroll
        for (int nj = 0; nj < 4; ++nj)
            #pragma unroll
            for (int rg = 0; rg < 4; ++rg) {
                const size_t m = mbase + mi * 16 + rg;
                const size_t n = nbase + nj * 16;
                if (BF16OUT)
                    ((short*)Cv)[m * N + n] = f2bf(acc[mi][nj][rg]);
                else
                    ((float*)Cv)[m * N + n] = acc[mi][nj][rg];
            }
}

// ---------------------------------------------------------------------------
// RoPE on bf16 QKV buffer (Q scaled by 1/8). (unchanged, passing)
// ---------------------------------------------------------------------------
__global__ __launch_bounds__(256)
void rope_bf16(const short* __restrict__ QKVr, const int* __restrict__ pos,
               short* __restrict__ Qh, short* __restrict__ Kh, int S, int rows) {
    int idx = blockIdx.x * 256 + threadIdx.x;
    const int per = rows * (DM / 2);
    bool isK = false;
    if (idx >= per) { idx -= per; isK = true; }
    if (idx >= per) return;
    const int row = idx >> 9;
    const int rem = idx & 511;
    const int h = rem >> 5, k = rem & 31;
    const unsigned pin = *(const unsigned*)(QKVr + (size_t)row * QKV +
                                            (isK ? DM : 0) + h * DH + 2 * k);
    const float x0 = __uint_as_float(pin << 16);
    const float x1 = __uint_as_float(pin & 0xffff0000u);
    const float ang = (float)pos[row % S] * powf(10000.0f, -(float)k * (1.0f / 32.0f));
    const float c = cosf(ang), sn = sinf(ang);
    float y0 = c * x0 - sn * x1;
    float y1 = sn * x0 + c * x1;
    if (!isK) { y0 *= 0.125f; y1 *= 0.125f; }
    const int b = row / S, sr = row % S;
    short* dst = (isK ? Kh : Qh) + ((size_t)(b * NH + h) * S + sr) * DH + 2 * k;
    *(unsigned*)dst = ((unsigned)(unsigned short)f2bf(y1) << 16)
                    | (unsigned short)f2bf(y0);
}

// ---------------------------------------------------------------------------
// V slice of QKV buffer -> per-head transposed Vt[B*H][64][S]. (unchanged)
// ---------------------------------------------------------------------------
__global__ __launch_bounds__(256)
void v_transpose_bf16(const short* __restrict__ QKVr, short* __restrict__ Vt, int S) {
    __shared__ __align__(16) short T[64][72];
    const int bh = blockIdx.y;
    const int b = bh / NH, h = bh - b * NH;
    const int s0 = blockIdx.x * 64;
    const int tid = threadIdx.x;
    const int r = tid >> 2, seg = (tid & 3) * 16;
    const short* src = QKVr + (size_t)(b * S + s0 + r) * QKV + 2 * DM + h * DH + seg;
    const short8v a0 = *(const short8v*)(src);
    const short8v a1 = *(const short8v*)(src + 8);
    #pragma unroll
    for (int j = 0; j < 8; ++j) T[seg + j][r] = a0[j];
    #pragma unroll
    for (int j = 0; j < 8; ++j) T[seg + 8 + j][r] = a1[j];
    __syncthreads();
    const uint4* sv = (const uint4*)&T[r][seg];
    uint4* dv = (uint4*)&Vt[((size_t)bh * DH + r) * S + s0 + seg];
    dv[0] = sv[0]; dv[1] = sv[1];
}

// ---------------------------------------------------------------------------
// MFMA flash attention, R11 = R7 dataflow + KV-split + XCD-aware swizzle.
//  - 256 thr = 4 waves = 2 pairs x 2 halves; half h does kv blocks of
//    parity h within the pair-interleaved kb loop (K/V frags shared by
//    B and F tiles; V issued early, hides under softmax).
//  - XCD swizzle: flat blockIdx -> (bh, blk) with flat%8 == bh%8, so each
//    XCD serves 4 (b,h) groups -> K/V working set 2 MB, fits 4 MB L2.
//    Correctness is placement-independent (speed heuristic only).
//  - combine: 3 block barriers; MB reused per tile; exact fp32 flash merge
//    (verified in R9/R10); empty-half contributes exactly 0.
// ---------------------------------------------------------------------------
__global__ __launch_bounds__(256)
void attn_mfma(const short* __restrict__ Qh, const short* __restrict__ Kh,
               const short* __restrict__ Vt, short* __restrict__ Oh,
               int S, int bpb) {
    __shared__ __align__(16) __hip_bfloat16 P[4][2][16][72];   // 18432 B
    __shared__ __align__(16) float MB[2][64][24];              // 12288 B

    const int tid = threadIdx.x;
    const int w = tid >> 6, l = tid & 63;
    const int pw = w >> 1, half = w & 1;
    const int lo = l & 15, hi = l >> 4;
    const int T = S >> 4;

    // XCD-aware decode: flat = (bh&7) + 8*((bh>>3)*bpb + blk)
    const int flat = blockIdx.x;
    const int bh3 = flat & 7;
    const int r = flat >> 3;
    const int grp = r / bpb, blk = r - grp * bpb;
    const int bh = grp * 8 + bh3;
    const int b = bh >> 4, h = bh & 15;          // NH = 16
    const int p = blk * 2 + pw;

    const int q0B = (T - 1 - p) << 4;
    const int q0F = p << 4;
    const int nkbB = (q0B + 79) >> 6;
    const int nkbF = (q0F + 79) >> 6;

    const short* Qp = Qh + (size_t)bh * S * DH;
    const short* Kp = Kh + (size_t)bh * S * DH;
    const short* Vp = Vt + (size_t)bh * DH * S;

    const short8v qB0 = *(const short8v*)(Qp + (size_t)(q0B + lo) * DH + hi * 8);
    const short8v qB1 = *(const short8v*)(Qp + (size_t)(q0B + lo) * DH + 32 + hi * 8);
    const short8v qF0 = *(const short8v*)(Qp + (size_t)(q0F + lo) * DH + hi * 8);
    const short8v qF1 = *(const short8v*)(Qp + (size_t)(q0F + lo) * DH + 32 + hi * 8);

    short8v ones;
    #pragma unroll
    for (int i = 0; i < 8; ++i) ones[i] = (short)0x3F80;   // bf16 1.0

    f32x4 oB[4], oF[4];
    f32x4 laB = (f32x4){0.f, 0.f, 0.f, 0.f};
    f32x4 laF = (f32x4){0.f, 0.f, 0.f, 0.f};
    float mB[4], mF[4];
    #pragma unroll
    for (int i = 0; i < 4; ++i) {
        oB[i] = (f32x4){0.f, 0.f, 0.f, 0.f};
        oF[i] = (f32x4){0.f, 0.f, 0.f, 0.f};
        mB[i] = -INFINITY; mF[i] = -INFINITY;
    }
    const f32x4 z = (f32x4){0.f, 0.f, 0.f, 0.f};
    const float THR = 8.0f;

    auto softmaxTile = [&](f32x4 (&s)[4], f32x4 (&o)[4], f32x4& la,
                           float (&m)[4], bool masked, int q0, int kvb, int tsel) {
        float sv[4][4], pmax[4];
        #pragma unroll
        for (int rg = 0; rg < 4; ++rg) {
            #pragma unroll
            for (int kt = 0; kt < 4; ++kt) {
                float v = s[kt][rg];
                if (masked && (kvb + kt * 16 + lo > q0 + hi * 4 + rg)) v = -INFINITY;
                sv[rg][kt] = v;
            }
            pmax[rg] = fmaxf(fmaxf(sv[rg][0], sv[rg][1]),
                             fmaxf(sv[rg][2], sv[rg][3]));
        }
        int need = 0;
        #pragma unroll
        for (int rg = 0; rg < 4; ++rg) need |= (pmax[rg] > m[rg] + THR);
        if (__any(need)) {
            #pragma unroll
            for (int rg = 0; rg < 4; ++rg) {
                float bm = pmax[rg];
                bm = fmaxf(bm, __shfl_xor(bm, 1));
                bm = fmaxf(bm, __shfl_xor(bm, 2));
                bm = fmaxf(bm, __shfl_xor(bm, 4));
                bm = fmaxf(bm, __shfl_xor(bm, 8));
                const float mn = fmaxf(m[rg], bm);
                const float c = __expf(m[rg] - mn);
                m[rg] = mn;
                la[rg] *= c;
                #pragma unroll
                for (int dt = 0; dt < 4; ++dt) o[dt][rg] *= c;
            }
        }
        #pragma unroll
        for (int rg = 0; rg < 4; ++rg)
            #pragma unroll
            for (int kt = 0; kt < 4; ++kt)
                P[w][tsel][hi * 4 + rg][kt * 16 + lo] =
                    __float2bfloat16(__expf(sv[rg][kt] - m[rg]));
    };

    for (int kb = half; kb < nkbB; kb += 2) {
        const int kvb = kb * 64;
        const bool actF = kb < nkbF;

        // ---- K fragments (shared by both tiles)
        short8v kf0[4], kf1[4];
        #pragma unroll
        for (int kt = 0; kt < 4; ++kt) {
            const short* kbase = Kp + (size_t)(kvb + kt * 16 + lo) * DH + hi * 8;
            kf0[kt] = *(const short8v*)(kbase);
            kf1[kt] = *(const short8v*)(kbase + 32);
        }
        // ---- V fragments, issued early: latency hides under softmax
        short8v vf0[4], vf1[4];
        #pragma unroll
        for (int dt = 0; dt < 4; ++dt) {
            const short* vbase = Vp + (size_t)(dt * 16 + lo) * S + kvb + hi * 8;
            vf0[dt] = *(const short8v*)(vbase);
            vf1[dt] = *(const short8v*)(vbase + 32);
        }

        // ---- QK^T, both tiles
        f32x4 sB[4], sF[4];
        #pragma unroll
        for (int kt = 0; kt < 4; ++kt) {
            f32x4 a = z;
            a = __builtin_amdgcn_mfma_f32_16x16x32_bf16(qB0, kf0[kt], a, 0, 0, 0);
            a = __builtin_amdgcn_mfma_f32_16x16x32_bf16(qB1, kf1[kt], a, 0, 0, 0);
            sB[kt] = a;
        }
        if (actF) {
            #pragma unroll
            for (int kt = 0; kt < 4; ++kt) {
                f32x4 a = z;
                a = __builtin_amdgcn_mfma_f32_16x16x32_bf16(qF0, kf0[kt], a, 0, 0, 0);
                a = __builtin_amdgcn_mfma_f32_16x16x32_bf16(qF1, kf1[kt], a, 0, 0, 0);
                sF[kt] = a;
            }
        }

        // ---- softmax (defer-max), mask only on each tile's last block
        softmaxTile(sB, oB, laB, mB, kb == nkbB - 1, q0B, kvb, 0);
        if (actF) softmaxTile(sF, oF, laF, mF, kb == nkbF - 1, q0F, kvb, 1);

        asm volatile("s_waitcnt lgkmcnt(0)" ::: "memory");
        const short8v paB0 = *(const short8v*)&P[w][0][lo][hi * 8];
        const short8v paB1 = *(const short8v*)&P[w][0][lo][32 + hi * 8];
        const short8v paF0 = *(const short8v*)&P[w][1][lo][hi * 8];
        const short8v paF1 = *(const short8v*)&P[w][1][lo][32 + hi * 8];

        // ---- row-sum via MFMA
        laB = __builtin_amdgcn_mfma_f32_16x16x32_bf16(paB0, ones, laB, 0, 0, 0);
        laB = __builtin_amdgcn_mfma_f32_16x16x32_bf16(paB1, ones, laB, 0, 0, 0);
        if (actF) {
            laF = __builtin_amdgcn_mfma_f32_16x16x32_bf16(paF0, ones, laF, 0, 0, 0);
            laF = __builtin_amdgcn_mfma_f32_16x16x32_bf16(paF1, ones, laF, 0, 0, 0);
        }

        // ---- PV, both tiles, shared V fragments
        #pragma unroll
        for (int dt = 0; dt < 4; ++dt) {
            oB[dt] = __builtin_amdgcn_mfma_f32_16x16x32_bf16(paB0, vf0[dt], oB[dt], 0, 0, 0);
            oB[dt] = __builtin_amdgcn_mfma_f32_16x16x32_bf16(paB1, vf1[dt], oB[dt], 0, 0, 0);
            if (actF) {
                oF[dt] = __builtin_amdgcn_mfma_f32_16x16x32_bf16(paF0, vf0[dt], oF[dt], 0, 0, 0);
                oF[dt] = __builtin_amdgcn_mfma_f32_16x16x32_bf16(paF1, vf1[dt], oF[dt], 0, 0, 0);
            }
        }
    }

    // ---- KV-split combine (MB reused per tile; spill-free constant code) ----
#define STORE_TILE(OT, MT, LAT)                                            \
    do {                                                                   \
        f32x4* dst = (f32x4*)&MB[pw][l][0];                                \
        dst[0] = OT[0]; dst[1] = OT[1]; dst[2] = OT[2]; dst[3] = OT[3];    \
        dst[4] = (f32x4){MT[0], MT[1], MT[2], MT[3]};                      \
        dst[5] = LAT;                                                      \
    } while (0)

#define MERGE_TILE(OT, MT, LAT, Q0T)                                       \
    do {                                                                   \
        const f32x4* src = (const f32x4*)&MB[pw][l][0];                    \
        const f32x4 o1_0 = src[0], o1_1 = src[1], o1_2 = src[2], o1_3 = src[3]; \
        const f32x4 m1 = src[4];                                           \
        const f32x4 la1 = src[5];                                          \
        short* Op = Oh + (size_t)(b * S + (Q0T)) * DM + h * DH;            \
        _Pragma("unroll")                                                  \
        for (int rg = 0; rg < 4; ++rg) {                                   \
            const float mst = fmaxf(MT[rg], m1[rg]);                       \
            const float c0 = __expf(MT[rg] - mst);                         \
            const float c1 = __expf(m1[rg] - mst);                         \
            const float iv = 1.0f / (LAT[rg] * c0 + la1[rg] * c1);         \
            Op[(size_t)(hi * 4 + rg) * DM +  0 + lo] = f2bf((OT[0][rg] * c0 + o1_0[rg] * c1) * iv); \
            Op[(size_t)(hi * 4 + rg) * DM + 16 + lo] = f2bf((OT[1][rg] * c0 + o1_1[rg] * c1) * iv); \
            Op[(size_t)(hi * 4 + rg) * DM + 32 + lo] = f2bf((OT[2][rg] * c0 + o1_2[rg] * c1) * iv); \
            Op[(size_t)(hi * 4 + rg) * DM + 48 + lo] = f2bf((OT[3][rg] * c0 + o1_3[rg] * c1) * iv); \
        }                                                                  \
    } while (0)

    if (half == 1) STORE_TILE(oB, mB, laB);
    __syncthreads();
    if (half == 0) MERGE_TILE(oB, mB, laB, q0B);
    __syncthreads();
    if (half == 1) STORE_TILE(oF, mF, laF);
    __syncthreads();
    if (half == 0) MERGE_TILE(oF, mF, laF, q0F);
#undef STORE_TILE
#undef MERGE_TILE
}

// ---------------------------------------------------------------------------
extern "C" void kernel_launch(void* const* d_in, const int* in_sizes, int n_in,
                              void* d_out, int out_size, void* d_ws, size_t ws_size,
                              hipStream_t stream) {
    const float* x  = (const float*)d_in[0];
    const int*  pos = (const int*)d_in[1];
    const float* wq = (const float*)d_in[2];
    const float* wk = (const float*)d_in[3];
    const float* wv = (const float*)d_in[4];
    const float* wo = (const float*)d_in[5];
    float* out = (float*)d_out;

    const int S = in_sizes[1];              // 2048
    const int rows = in_sizes[0] / DM;      // B*S
    const int Bb = rows / S;

    short* xh   = (short*)d_ws;
    short* wqkv = xh + (size_t)rows * DM;
    short* woh  = wqkv + (size_t)QKV * DM;
    short* QKVr = woh + (size_t)DM * DM;
    short* Qh   = QKVr + (size_t)rows * QKV;
    short* Kh   = Qh + (size_t)rows * DM;
    short* Vt   = Kh + (size_t)rows * DM;
    short* Oh   = Vt + (size_t)rows * DM;

    const int nx = rows * DM;
    const int nw = DM * DM;
    const int ntot = nx + 4 * nw;
    convert_inputs<<<(ntot / 4 + 255) / 256, 256, 0, stream>>>(
        x, wq, wk, wv, wo, xh, wqkv, woh, nx, nw);

    gemm_bt_mfma<1><<<dim3(QKV / 128, rows / 128), 256, 0, stream>>>(
        xh, wqkv, QKVr, rows, QKV, DM);

    const int total = 2 * rows * (DM / 2);
    rope_bf16<<<(total + 255) / 256, 256, 0, stream>>>(QKVr, pos, Qh, Kh, S, rows);
    v_transpose_bf16<<<dim3(S / 64, Bb * NH), 256, 0, stream>>>(QKVr, Vt, S);

    // XCD-swizzled 1D grid: nbh * bpb blocks, flat%8 selects bh%8.
    const int Tq = S / 16;
    const int bpb = Tq / 4;                 // blocks per (b,h): 2 pairs/block
    const int nbh = Bb * NH;
    attn_mfma<<<dim3(nbh * bpb), 256, 0, stream>>>(Qh, Kh, Vt, Oh, S, bpb);

    gemm_bt_mfma<0><<<dim3(DM / 128, rows / 128), 256, 0, stream>>>(
        Oh, woh, out, rows, DM, DM);
}

// Round 12
// 208.640 us; speedup vs baseline: 1.4412x; 1.0013x over previous
//
#include <hip/hip_runtime.h>
#include <hip/hip_bf16.h>
#include <math.h>

static constexpr int DM = 1024;   // d_model
static constexpr int NH = 16;     // heads
static constexpr int DH = 64;     // head dim
static constexpr int QKV = 3 * DM;

typedef __attribute__((ext_vector_type(8))) short short8v;  // 8 bf16 = 4 VGPR
typedef __attribute__((ext_vector_type(4))) float f32x4;

__device__ inline short f2bf(float x) {
    __hip_bfloat16 h = __float2bfloat16(x);
    return *reinterpret_cast<short*>(&h);
}

// pack two f32 -> u32 of 2 bf16 (lo word = first arg), RNE
__device__ inline unsigned cvtpk(float a, float b) {
    unsigned r;
    asm("v_cvt_pk_bf16_f32 %0, %1, %2" : "=v"(r) : "v"(a), "v"(b));
    return r;
}

// pull f32 from srclane (0..63)
__device__ inline float bperm_f(int srclane, float v) {
    return __int_as_float(
        __builtin_amdgcn_ds_bpermute(srclane << 2, __float_as_int(v)));
}

// async global->LDS, 16B per lane. LDS dst must be wave-uniform (HW writes
// lane i at dst + i*16); global src is per-lane.
__device__ inline void gload16(const void* g, void* l) {
    __builtin_amdgcn_global_load_lds(
        (const __attribute__((address_space(1))) unsigned int*)g,
        (__attribute__((address_space(3))) unsigned int*)l, 16, 0, 0);
}

// ---------------------------------------------------------------------------
// Fused fp32 -> bf16 convert for all five inputs (one launch).
// ---------------------------------------------------------------------------
__global__ __launch_bounds__(256)
void convert_inputs(const float* __restrict__ x,  const float* __restrict__ wq,
                    const float* __restrict__ wk, const float* __restrict__ wv,
                    const float* __restrict__ wo, short* __restrict__ xh,
                    short* __restrict__ wqkv, short* __restrict__ woh,
                    int nx, int nw) {
    const int i = (blockIdx.x * 256 + threadIdx.x) * 4;
    const float* src;
    short* dst;
    int off;
    if (i < nx)                { src = x;  dst = xh;            off = i; }
    else if (i < nx + nw)      { src = wq; dst = wqkv;          off = i - nx; }
    else if (i < nx + 2 * nw)  { src = wk; dst = wqkv + nw;     off = i - nx - nw; }
    else if (i < nx + 3 * nw)  { src = wv; dst = wqkv + 2 * nw; off = i - nx - 2 * nw; }
    else if (i < nx + 4 * nw)  { src = wo; dst = woh;           off = i - nx - 3 * nw; }
    else return;
    const float4 v = *(const float4*)(src + off);
    short4 o;
    o.x = f2bf(v.x); o.y = f2bf(v.y); o.z = f2bf(v.z); o.w = f2bf(v.w);
    *(short4*)(dst + off) = o;
}

// ---------------------------------------------------------------------------
// bf16 MFMA GEMM, m97 structure (unchanged, passing).
// ---------------------------------------------------------------------------
template <int BF16OUT>
__global__ __launch_bounds__(256)
void gemm_bt_mfma(const short* __restrict__ A, const short* __restrict__ B,
                  void* __restrict__ Cv, int M, int N, int K) {
    __shared__ __align__(16) short As[128 * 32];
    __shared__ __align__(16) short Bs[128 * 32];
    const int tid = threadIdx.x;
    const int w = tid >> 6, l = tid & 63;
    const int lo = l & 15, hi = l >> 4;
    const int wr = w >> 1, wc = w & 1;
    const size_t m0 = (size_t)blockIdx.y * 128;
    const size_t n0 = (size_t)blockIdx.x * 128;

    const int cr = (w * 2) * 16 + (l >> 2);
    const int cc = (l & 3) * 8;
    const short* Ag0 = A + (m0 + cr) * K + cc;
    const short* Ag1 = Ag0 + (size_t)16 * K;
    const short* Bg0 = B + (n0 + cr) * K + cc;
    const short* Bg1 = Bg0 + (size_t)16 * K;
    short* As0 = As + (w * 2) * 512;
    short* As1 = As0 + 512;
    short* Bs0 = Bs + (w * 2) * 512;
    short* Bs1 = Bs0 + 512;

    f32x4 acc[4][4];
    #pragma unroll
    for (int mi = 0; mi < 4; ++mi)
        #pragma unroll
        for (int nj = 0; nj < 4; ++nj)
            acc[mi][nj] = (f32x4){0.f, 0.f, 0.f, 0.f};

    const int aoff = (wr * 64 + lo) * 32 + hi * 8;
    const int boff = (wc * 64 + lo) * 32 + hi * 8;

    for (int k0 = 0; k0 < K; k0 += 32) {
        __syncthreads();
        gload16(Ag0 + k0, As0);
        gload16(Ag1 + k0, As1);
        gload16(Bg0 + k0, Bs0);
        gload16(Bg1 + k0, Bs1);
        __syncthreads();
        short8v af[4], bf[4];
        #pragma unroll
        for (int mi = 0; mi < 4; ++mi)
            af[mi] = *(const short8v*)&As[aoff + mi * 16 * 32];
        #pragma unroll
        for (int nj = 0; nj < 4; ++nj)
            bf[nj] = *(const short8v*)&Bs[boff + nj * 16 * 32];
        #pragma unroll
        for (int mi = 0; mi < 4; ++mi)
            #pragma unroll
            for (int nj = 0; nj < 4; ++nj)
                acc[mi][nj] = __builtin_amdgcn_mfma_f32_16x16x32_bf16(
                    af[mi], bf[nj], acc[mi][nj], 0, 0, 0);
    }

    const size_t mbase = m0 + wr * 64 + hi * 4;
    const size_t nbase = n0 + wc * 64 + lo;
    #pragma unroll
    for (int mi = 0; mi < 4; ++mi)
        #pragma unroll
        for (int nj = 0; nj < 4; ++nj)
            #pragma unroll
            for (int rg = 0; rg < 4; ++rg) {
                const size_t m = mbase + mi * 16 + rg;
                const size_t n = nbase + nj * 16;
                if (BF16OUT)
                    ((short*)Cv)[m * N + n] = f2bf(acc[mi][nj][rg]);
                else
                    ((float*)Cv)[m * N + n] = acc[mi][nj][rg];
            }
}

// ---------------------------------------------------------------------------
// RoPE on bf16 QKV buffer (Q scaled by 1/8). (unchanged, passing)
// ---------------------------------------------------------------------------
__global__ __launch_bounds__(256)
void rope_bf16(const short* __restrict__ QKVr, const int* __restrict__ pos,
               short* __restrict__ Qh, short* __restrict__ Kh, int S, int rows) {
    int idx = blockIdx.x * 256 + threadIdx.x;
    const int per = rows * (DM / 2);
    bool isK = false;
    if (idx >= per) { idx -= per; isK = true; }
    if (idx >= per) return;
    const int row = idx >> 9;
    const int rem = idx & 511;
    const int h = rem >> 5, k = rem & 31;
    const unsigned pin = *(const unsigned*)(QKVr + (size_t)row * QKV +
                                            (isK ? DM : 0) + h * DH + 2 * k);
    const float x0 = __uint_as_float(pin << 16);
    const float x1 = __uint_as_float(pin & 0xffff0000u);
    const float ang = (float)pos[row % S] * powf(10000.0f, -(float)k * (1.0f / 32.0f));
    const float c = cosf(ang), sn = sinf(ang);
    float y0 = c * x0 - sn * x1;
    float y1 = sn * x0 + c * x1;
    if (!isK) { y0 *= 0.125f; y1 *= 0.125f; }
    const int b = row / S, sr = row % S;
    short* dst = (isK ? Kh : Qh) + ((size_t)(b * NH + h) * S + sr) * DH + 2 * k;
    *(unsigned*)dst = ((unsigned)(unsigned short)f2bf(y1) << 16)
                    | (unsigned short)f2bf(y0);
}

// ---------------------------------------------------------------------------
// V slice of QKV buffer -> per-head transposed Vt[B*H][64][S]. (unchanged)
// ---------------------------------------------------------------------------
__global__ __launch_bounds__(256)
void v_transpose_bf16(const short* __restrict__ QKVr, short* __restrict__ Vt, int S) {
    __shared__ __align__(16) short T[64][72];
    const int bh = blockIdx.y;
    const int b = bh / NH, h = bh - b * NH;
    const int s0 = blockIdx.x * 64;
    const int tid = threadIdx.x;
    const int r = tid >> 2, seg = (tid & 3) * 16;
    const short* src = QKVr + (size_t)(b * S + s0 + r) * QKV + 2 * DM + h * DH + seg;
    const short8v a0 = *(const short8v*)(src);
    const short8v a1 = *(const short8v*)(src + 8);
    #pragma unroll
    for (int j = 0; j < 8; ++j) T[seg + j][r] = a0[j];
    #pragma unroll
    for (int j = 0; j < 8; ++j) T[seg + 8 + j][r] = a1[j];
    __syncthreads();
    const uint4* sv = (const uint4*)&T[r][seg];
    uint4* dv = (uint4*)&Vt[((size_t)bh * DH + r) * S + s0 + seg];
    dv[0] = sv[0]; dv[1] = sv[1];
}

// ---------------------------------------------------------------------------
// MFMA flash attention, R12 = R11 + SWAPPED QK^T in-register softmax (T12).
//  - sT = mfma(K, Q): lane holds S[q = q0+lo][k = kvb + kt*16 + hi*4 + rg]
//    -> row max/sum are lane-local trees + 2 shfl_xor(16/32).
//  - P -> A-frag: 8 cvt_pk (rg pairs are k-adjacent) + 4 ds_write_b64 into
//    P2[16][36] u32 (pad 4: rows 144 B, b128-aligned, conflict-free reads)
//    + 2 ds_read_b128. Write col kt*8+hi*2+rgp <-> read col hi*4+j verified.
//  - PV/O layout unchanged (pa is the A operand); rescale c and final m
//    cross q=lo -> row layout via ds_bpermute.
//  - everything else (KV-split, XCD swizzle, defer-max, MFMA row-sum,
//    mask-hoist, merge) identical to passing R11.
// ---------------------------------------------------------------------------
__global__ __launch_bounds__(256)
void attn_mfma(const short* __restrict__ Qh, const short* __restrict__ Kh,
               const short* __restrict__ Vt, short* __restrict__ Oh,
               int S, int bpb) {
    __shared__ __align__(16) unsigned P2[4][2][16][36];   // 18432 B
    __shared__ __align__(16) float MB[2][64][24];         // 12288 B

    const int tid = threadIdx.x;
    const int w = tid >> 6, l = tid & 63;
    const int pw = w >> 1, half = w & 1;
    const int lo = l & 15, hi = l >> 4;
    const int T = S >> 4;

    // XCD-aware decode: flat = (bh&7) + 8*((bh>>3)*bpb + blk)
    const int flat = blockIdx.x;
    const int bh3 = flat & 7;
    const int r = flat >> 3;
    const int grp = r / bpb, blk = r - grp * bpb;
    const int bh = grp * 8 + bh3;
    const int b = bh >> 4, h = bh & 15;          // NH = 16
    const int p = blk * 2 + pw;

    const int q0B = (T - 1 - p) << 4;
    const int q0F = p << 4;
    const int nkbB = (q0B + 79) >> 6;
    const int nkbF = (q0F + 79) >> 6;

    const short* Qp = Qh + (size_t)bh * S * DH;
    const short* Kp = Kh + (size_t)bh * S * DH;
    const short* Vp = Vt + (size_t)bh * DH * S;

    const short8v qB0 = *(const short8v*)(Qp + (size_t)(q0B + lo) * DH + hi * 8);
    const short8v qB1 = *(const short8v*)(Qp + (size_t)(q0B + lo) * DH + 32 + hi * 8);
    const short8v qF0 = *(const short8v*)(Qp + (size_t)(q0F + lo) * DH + hi * 8);
    const short8v qF1 = *(const short8v*)(Qp + (size_t)(q0F + lo) * DH + 32 + hi * 8);

    short8v ones;
    #pragma unroll
    for (int i = 0; i < 8; ++i) ones[i] = (short)0x3F80;   // bf16 1.0

    f32x4 oB[4], oF[4];
    f32x4 laB = (f32x4){0.f, 0.f, 0.f, 0.f};
    f32x4 laF = (f32x4){0.f, 0.f, 0.f, 0.f};
    float mB = -INFINITY, mF = -INFINITY;   // per-lane running max (q = q0+lo)
    #pragma unroll
    for (int i = 0; i < 4; ++i) {
        oB[i] = (f32x4){0.f, 0.f, 0.f, 0.f};
        oF[i] = (f32x4){0.f, 0.f, 0.f, 0.f};
    }
    const f32x4 z = (f32x4){0.f, 0.f, 0.f, 0.f};

    // in-register softmax for one tile (swapped layout), then P2 store
    auto softmaxTile = [&](const f32x4 (&s)[4], float& m, f32x4 (&o)[4],
                           f32x4& la, bool masked, int q0, int kvb, int tsel) {
        float pv[16];
        float bm = -INFINITY;
        const int lim = q0 + lo - kvb;   // unmasked iff kt*16+hi*4+rg <= lim
        #pragma unroll
        for (int kt = 0; kt < 4; ++kt)
            #pragma unroll
            for (int rg = 0; rg < 4; ++rg) {
                float v = s[kt][rg];
                if (masked && (kt * 16 + hi * 4 + rg > lim)) v = -INFINITY;
                pv[kt * 4 + rg] = v;
                bm = fmaxf(bm, v);
            }
        bm = fmaxf(bm, __shfl_xor(bm, 16));
        bm = fmaxf(bm, __shfl_xor(bm, 32));
        if (__any(bm > m + 8.0f)) {
            const float mn = fmaxf(m, bm);
            const float c = __expf(m - mn);
            m = mn;
            #pragma unroll
            for (int rg = 0; rg < 4; ++rg) {
                const float cr = bperm_f(hi * 4 + rg, c);
                la[rg] *= cr;
                #pragma unroll
                for (int dt = 0; dt < 4; ++dt) o[dt][rg] *= cr;
            }
        }
        #pragma unroll
        for (int kt = 0; kt < 4; ++kt) {
            uint2 wv;
            wv.x = cvtpk(__expf(pv[kt * 4 + 0] - m), __expf(pv[kt * 4 + 1] - m));
            wv.y = cvtpk(__expf(pv[kt * 4 + 2] - m), __expf(pv[kt * 4 + 3] - m));
            *(uint2*)&P2[w][tsel][lo][kt * 8 + hi * 2] = wv;
        }
    };

    for (int kb = half; kb < nkbB; kb += 2) {
        const int kvb = kb * 64;
        const bool actF = kb < nkbF;

        // ---- K fragments (shared by both tiles)
        short8v kf0[4], kf1[4];
        #pragma unroll
        for (int kt = 0; kt < 4; ++kt) {
            const short* kbase = Kp + (size_t)(kvb + kt * 16 + lo) * DH + hi * 8;
            kf0[kt] = *(const short8v*)(kbase);
            kf1[kt] = *(const short8v*)(kbase + 32);
        }
        // ---- V fragments, issued early: latency hides under softmax
        short8v vf0[4], vf1[4];
        #pragma unroll
        for (int dt = 0; dt < 4; ++dt) {
            const short* vbase = Vp + (size_t)(dt * 16 + lo) * S + kvb + hi * 8;
            vf0[dt] = *(const short8v*)(vbase);
            vf1[dt] = *(const short8v*)(vbase + 32);
        }

        // ---- tile B: swapped QK^T -> in-register softmax -> P2
        {
            f32x4 sB[4];
            #pragma unroll
            for (int kt = 0; kt < 4; ++kt) {
                f32x4 a = z;
                a = __builtin_amdgcn_mfma_f32_16x16x32_bf16(kf0[kt], qB0, a, 0, 0, 0);
                a = __builtin_amdgcn_mfma_f32_16x16x32_bf16(kf1[kt], qB1, a, 0, 0, 0);
                sB[kt] = a;
            }
            softmaxTile(sB, mB, oB, laB, kb == nkbB - 1, q0B, kvb, 0);
        }
        // ---- tile F
        if (actF) {
            f32x4 sF[4];
            #pragma unroll
            for (int kt = 0; kt < 4; ++kt) {
                f32x4 a = z;
                a = __builtin_amdgcn_mfma_f32_16x16x32_bf16(kf0[kt], qF0, a, 0, 0, 0);
                a = __builtin_amdgcn_mfma_f32_16x16x32_bf16(kf1[kt], qF1, a, 0, 0, 0);
                sF[kt] = a;
            }
            softmaxTile(sF, mF, oF, laF, kb == nkbF - 1, q0F, kvb, 1);
        }

        asm volatile("s_waitcnt lgkmcnt(0)" ::: "memory");
        const short8v paB0 = *(const short8v*)&P2[w][0][lo][hi * 4];
        const short8v paB1 = *(const short8v*)&P2[w][0][lo][16 + hi * 4];

        // ---- row-sum via MFMA (row layout, matches o)
        laB = __builtin_amdgcn_mfma_f32_16x16x32_bf16(paB0, ones, laB, 0, 0, 0);
        laB = __builtin_amdgcn_mfma_f32_16x16x32_bf16(paB1, ones, laB, 0, 0, 0);
        #pragma unroll
        for (int dt = 0; dt < 4; ++dt) {
            oB[dt] = __builtin_amdgcn_mfma_f32_16x16x32_bf16(paB0, vf0[dt], oB[dt], 0, 0, 0);
            oB[dt] = __builtin_amdgcn_mfma_f32_16x16x32_bf16(paB1, vf1[dt], oB[dt], 0, 0, 0);
        }
        if (actF) {
            const short8v paF0 = *(const short8v*)&P2[w][1][lo][hi * 4];
            const short8v paF1 = *(const short8v*)&P2[w][1][lo][16 + hi * 4];
            laF = __builtin_amdgcn_mfma_f32_16x16x32_bf16(paF0, ones, laF, 0, 0, 0);
            laF = __builtin_amdgcn_mfma_f32_16x16x32_bf16(paF1, ones, laF, 0, 0, 0);
            #pragma unroll
            for (int dt = 0; dt < 4; ++dt) {
                oF[dt] = __builtin_amdgcn_mfma_f32_16x16x32_bf16(paF0, vf0[dt], oF[dt], 0, 0, 0);
                oF[dt] = __builtin_amdgcn_mfma_f32_16x16x32_bf16(paF1, vf1[dt], oF[dt], 0, 0, 0);
            }
        }
    }

    // ---- m (per-lane, q=lo) -> row layout for the merge
    float mBr[4], mFr[4];
    #pragma unroll
    for (int rg = 0; rg < 4; ++rg) {
        mBr[rg] = bperm_f(hi * 4 + rg, mB);
        mFr[rg] = bperm_f(hi * 4 + rg, mF);
    }

    // ---- KV-split combine (identical structure to R11, spill-free) ----
#define STORE_TILE(OT, MT, LAT)                                            \
    do {                                                                   \
        f32x4* dst = (f32x4*)&MB[pw][l][0];                                \
        dst[0] = OT[0]; dst[1] = OT[1]; dst[2] = OT[2]; dst[3] = OT[3];    \
        dst[4] = (f32x4){MT[0], MT[1], MT[2], MT[3]};                      \
        dst[5] = LAT;                                                      \
    } while (0)

#define MERGE_TILE(OT, MT, LAT, Q0T)                                       \
    do {                                                                   \
        const f32x4* src = (const f32x4*)&MB[pw][l][0];                    \
        const f32x4 o1_0 = src[0], o1_1 = src[1], o1_2 = src[2], o1_3 = src[3]; \
        const f32x4 m1 = src[4];                                           \
        const f32x4 la1 = src[5];                                          \
        short* Op = Oh + (size_t)(b * S + (Q0T)) * DM + h * DH;            \
        _Pragma("unroll")                                                  \
        for (int rg = 0; rg < 4; ++rg) {                                   \
            const float mst = fmaxf(MT[rg], m1[rg]);                       \
            const float c0 = __expf(MT[rg] - mst);                         \
            const float c1 = __expf(m1[rg] - mst);                         \
            const float iv = 1.0f / (LAT[rg] * c0 + la1[rg] * c1);         \
            Op[(size_t)(hi * 4 + rg) * DM +  0 + lo] = f2bf((OT[0][rg] * c0 + o1_0[rg] * c1) * iv); \
            Op[(size_t)(hi * 4 + rg) * DM + 16 + lo] = f2bf((OT[1][rg] * c0 + o1_1[rg] * c1) * iv); \
            Op[(size_t)(hi * 4 + rg) * DM + 32 + lo] = f2bf((OT[2][rg] * c0 + o1_2[rg] * c1) * iv); \
            Op[(size_t)(hi * 4 + rg) * DM + 48 + lo] = f2bf((OT[3][rg] * c0 + o1_3[rg] * c1) * iv); \
        }                                                                  \
    } while (0)

    __syncthreads();
    if (half == 1) STORE_TILE(oB, mBr, laB);
    __syncthreads();
    if (half == 0) MERGE_TILE(oB, mBr, laB, q0B);
    __syncthreads();
    if (half == 1) STORE_TILE(oF, mFr, laF);
    __syncthreads();
    if (half == 0) MERGE_TILE(oF, mFr, laF, q0F);
#undef STORE_TILE
#undef MERGE_TILE
}

// ---------------------------------------------------------------------------
extern "C" void kernel_launch(void* const* d_in, const int* in_sizes, int n_in,
                              void* d_out, int out_size, void* d_ws, size_t ws_size,
                              hipStream_t stream) {
    const float* x  = (const float*)d_in[0];
    const int*  pos = (const int*)d_in[1];
    const float* wq = (const float*)d_in[2];
    const float* wk = (const float*)d_in[3];
    const float* wv = (const float*)d_in[4];
    const float* wo = (const float*)d_in[5];
    float* out = (float*)d_out;

    const int S = in_sizes[1];              // 2048
    const int rows = in_sizes[0] / DM;      // B*S
    const int Bb = rows / S;

    short* xh   = (short*)d_ws;
    short* wqkv = xh + (size_t)rows * DM;
    short* woh  = wqkv + (size_t)QKV * DM;
    short* QKVr = woh + (size_t)DM * DM;
    short* Qh   = QKVr + (size_t)rows * QKV;
    short* Kh   = Qh + (size_t)rows * DM;
    short* Vt   = Kh + (size_t)rows * DM;
    short* Oh   = Vt + (size_t)rows * DM;

    const int nx = rows * DM;
    const int nw = DM * DM;
    const int ntot = nx + 4 * nw;
    convert_inputs<<<(ntot / 4 + 255) / 256, 256, 0, stream>>>(
        x, wq, wk, wv, wo, xh, wqkv, woh, nx, nw);

    gemm_bt_mfma<1><<<dim3(QKV / 128, rows / 128), 256, 0, stream>>>(
        xh, wqkv, QKVr, rows, QKV, DM);

    const int total = 2 * rows * (DM / 2);
    rope_bf16<<<(total + 255) / 256, 256, 0, stream>>>(QKVr, pos, Qh, Kh, S, rows);
    v_transpose_bf16<<<dim3(S / 64, Bb * NH), 256, 0, stream>>>(QKVr, Vt, S);

    // XCD-swizzled 1D grid: nbh * bpb blocks, flat%8 selects bh%8.
    const int Tq = S / 16;
    const int bpb = Tq / 4;                 // blocks per (b,h): 2 pairs/block
    const int nbh = Bb * NH;
    attn_mfma<<<dim3(nbh * bpb), 256, 0, stream>>>(Qh, Kh, Vt, Oh, S, bpb);

    gemm_bt_mfma<0><<<dim3(DM / 128, rows / 128), 256, 0, stream>>>(
        Oh, woh, out, rows, DM, DM);
}

// Round 13
// 191.867 us; speedup vs baseline: 1.5672x; 1.0874x over previous
//
#include <hip/hip_runtime.h>
#include <hip/hip_bf16.h>
#include <math.h>

static constexpr int DM = 1024;   // d_model
static constexpr int NH = 16;     // heads
static constexpr int DH = 64;     // head dim
static constexpr int QKV = 3 * DM;

typedef __attribute__((ext_vector_type(8))) short short8v;  // 8 bf16 = 4 VGPR
typedef __attribute__((ext_vector_type(4))) float f32x4;

__device__ inline short f2bf(float x) {
    __hip_bfloat16 h = __float2bfloat16(x);
    return *reinterpret_cast<short*>(&h);
}

// pack two f32 -> u32 of 2 bf16 (lo word = first arg), RNE
__device__ inline unsigned cvtpk(float a, float b) {
    unsigned r;
    asm("v_cvt_pk_bf16_f32 %0, %1, %2" : "=v"(r) : "v"(a), "v"(b));
    return r;
}

// pull f32 from srclane (0..63)
__device__ inline float bperm_f(int srclane, float v) {
    return __int_as_float(
        __builtin_amdgcn_ds_bpermute(srclane << 2, __float_as_int(v)));
}

// async global->LDS, 16B per lane.
__device__ inline void gload16(const void* g, void* l) {
    __builtin_amdgcn_global_load_lds(
        (const __attribute__((address_space(1))) unsigned int*)g,
        (__attribute__((address_space(3))) unsigned int*)l, 16, 0, 0);
}

// ---------------------------------------------------------------------------
// Fused fp32 -> bf16 convert for all five inputs (one launch).
// ---------------------------------------------------------------------------
__global__ __launch_bounds__(256)
void convert_inputs(const float* __restrict__ x,  const float* __restrict__ wq,
                    const float* __restrict__ wk, const float* __restrict__ wv,
                    const float* __restrict__ wo, short* __restrict__ xh,
                    short* __restrict__ wqkv, short* __restrict__ woh,
                    int nx, int nw) {
    const int i = (blockIdx.x * 256 + threadIdx.x) * 4;
    const float* src;
    short* dst;
    int off;
    if (i < nx)                { src = x;  dst = xh;            off = i; }
    else if (i < nx + nw)      { src = wq; dst = wqkv;          off = i - nx; }
    else if (i < nx + 2 * nw)  { src = wk; dst = wqkv + nw;     off = i - nx - nw; }
    else if (i < nx + 3 * nw)  { src = wv; dst = wqkv + 2 * nw; off = i - nx - 2 * nw; }
    else if (i < nx + 4 * nw)  { src = wo; dst = woh;           off = i - nx - 3 * nw; }
    else return;
    const float4 v = *(const float4*)(src + off);
    short4 o;
    o.x = f2bf(v.x); o.y = f2bf(v.y); o.z = f2bf(v.z); o.w = f2bf(v.w);
    *(short4*)(dst + off) = o;
}

// ---------------------------------------------------------------------------
// bf16 MFMA GEMM, m97 structure (unchanged, passing).
// ---------------------------------------------------------------------------
template <int BF16OUT>
__global__ __launch_bounds__(256)
void gemm_bt_mfma(const short* __restrict__ A, const short* __restrict__ B,
                  void* __restrict__ Cv, int M, int N, int K) {
    __shared__ __align__(16) short As[128 * 32];
    __shared__ __align__(16) short Bs[128 * 32];
    const int tid = threadIdx.x;
    const int w = tid >> 6, l = tid & 63;
    const int lo = l & 15, hi = l >> 4;
    const int wr = w >> 1, wc = w & 1;
    const size_t m0 = (size_t)blockIdx.y * 128;
    const size_t n0 = (size_t)blockIdx.x * 128;

    const int cr = (w * 2) * 16 + (l >> 2);
    const int cc = (l & 3) * 8;
    const short* Ag0 = A + (m0 + cr) * K + cc;
    const short* Ag1 = Ag0 + (size_t)16 * K;
    const short* Bg0 = B + (n0 + cr) * K + cc;
    const short* Bg1 = Bg0 + (size_t)16 * K;
    short* As0 = As + (w * 2) * 512;
    short* As1 = As0 + 512;
    short* Bs0 = Bs + (w * 2) * 512;
    short* Bs1 = Bs0 + 512;

    f32x4 acc[4][4];
    #pragma unroll
    for (int mi = 0; mi < 4; ++mi)
        #pragma unroll
        for (int nj = 0; nj < 4; ++nj)
            acc[mi][nj] = (f32x4){0.f, 0.f, 0.f, 0.f};

    const int aoff = (wr * 64 + lo) * 32 + hi * 8;
    const int boff = (wc * 64 + lo) * 32 + hi * 8;

    for (int k0 = 0; k0 < K; k0 += 32) {
        __syncthreads();
        gload16(Ag0 + k0, As0);
        gload16(Ag1 + k0, As1);
        gload16(Bg0 + k0, Bs0);
        gload16(Bg1 + k0, Bs1);
        __syncthreads();
        short8v af[4], bf[4];
        #pragma unroll
        for (int mi = 0; mi < 4; ++mi)
            af[mi] = *(const short8v*)&As[aoff + mi * 16 * 32];
        #pragma unroll
        for (int nj = 0; nj < 4; ++nj)
            bf[nj] = *(const short8v*)&Bs[boff + nj * 16 * 32];
        #pragma unroll
        for (int mi = 0; mi < 4; ++mi)
            #pragma unroll
            for (int nj = 0; nj < 4; ++nj)
                acc[mi][nj] = __builtin_amdgcn_mfma_f32_16x16x32_bf16(
                    af[mi], bf[nj], acc[mi][nj], 0, 0, 0);
    }

    const size_t mbase = m0 + wr * 64 + hi * 4;
    const size_t nbase = n0 + wc * 64 + lo;
    #pragma unroll
    for (int mi = 0; mi < 4; ++mi)
        #pragma unroll
        for (int nj = 0; nj < 4; ++nj)
            #pragma unroll
            for (int rg = 0; rg < 4; ++rg) {
                const size_t m = mbase + mi * 16 + rg;
                const size_t n = nbase + nj * 16;
                if (BF16OUT)
                    ((short*)Cv)[m * N + n] = f2bf(acc[mi][nj][rg]);
                else
                    ((float*)Cv)[m * N + n] = acc[mi][nj][rg];
            }
}

// ---------------------------------------------------------------------------
// cos/sin table: cst[s*32+k] = {cos, sin}(pos[s] * 10000^(-k/32)).
// Same fp32 expressions as the old in-rope path -> bit-identical results.
// ---------------------------------------------------------------------------
__global__ __launch_bounds__(256)
void build_cs(const int* __restrict__ pos, float2* __restrict__ cst, int S) {
    const int i = blockIdx.x * 256 + threadIdx.x;
    if (i >= S * 32) return;
    const int s = i >> 5, k = i & 31;
    const float ang = (float)pos[s] * powf(10000.0f, -(float)k * (1.0f / 32.0f));
    cst[i] = make_float2(cosf(ang), sinf(ang));
}

// ---------------------------------------------------------------------------
// RoPE on bf16 QKV buffer (Q scaled by 1/8), trig from table.
// ---------------------------------------------------------------------------
__global__ __launch_bounds__(256)
void rope_bf16(const short* __restrict__ QKVr, const float2* __restrict__ cst,
               short* __restrict__ Qh, short* __restrict__ Kh, int S, int rows) {
    int idx = blockIdx.x * 256 + threadIdx.x;
    const int per = rows * (DM / 2);
    bool isK = false;
    if (idx >= per) { idx -= per; isK = true; }
    if (idx >= per) return;
    const int row = idx >> 9;
    const int rem = idx & 511;
    const int h = rem >> 5, k = rem & 31;
    const int b = row / S, sr = row - b * S;
    const unsigned pin = *(const unsigned*)(QKVr + (size_t)row * QKV +
                                            (isK ? DM : 0) + h * DH + 2 * k);
    const float x0 = __uint_as_float(pin << 16);
    const float x1 = __uint_as_float(pin & 0xffff0000u);
    const float2 cs = cst[sr * 32 + k];
    float y0 = cs.x * x0 - cs.y * x1;
    float y1 = cs.y * x0 + cs.x * x1;
    if (!isK) { y0 *= 0.125f; y1 *= 0.125f; }
    short* dst = (isK ? Kh : Qh) + ((size_t)(b * NH + h) * S + sr) * DH + 2 * k;
    *(unsigned*)dst = ((unsigned)(unsigned short)f2bf(y1) << 16)
                    | (unsigned short)f2bf(y0);
}

// ---------------------------------------------------------------------------
// V slice of QKV buffer -> per-head transposed Vt[B*H][64][S]. (unchanged)
// ---------------------------------------------------------------------------
__global__ __launch_bounds__(256)
void v_transpose_bf16(const short* __restrict__ QKVr, short* __restrict__ Vt, int S) {
    __shared__ __align__(16) short T[64][72];
    const int bh = blockIdx.y;
    const int b = bh / NH, h = bh - b * NH;
    const int s0 = blockIdx.x * 64;
    const int tid = threadIdx.x;
    const int r = tid >> 2, seg = (tid & 3) * 16;
    const short* src = QKVr + (size_t)(b * S + s0 + r) * QKV + 2 * DM + h * DH + seg;
    const short8v a0 = *(const short8v*)(src);
    const short8v a1 = *(const short8v*)(src + 8);
    #pragma unroll
    for (int j = 0; j < 8; ++j) T[seg + j][r] = a0[j];
    #pragma unroll
    for (int j = 0; j < 8; ++j) T[seg + 8 + j][r] = a1[j];
    __syncthreads();
    const uint4* sv = (const uint4*)&T[r][seg];
    uint4* dv = (uint4*)&Vt[((size_t)bh * DH + r) * S + s0 + seg];
    dv[0] = sv[0]; dv[1] = sv[1];
}

// ---------------------------------------------------------------------------
// MFMA flash attention, R13 = R12 + K-PREFETCH software pipeline.
// Ping-pong K register sets (kfA/kfB): iteration for kb issues loads for
// kb+2 right after its QK^T MFMAs, so K L2 latency (~200-400cy) hides
// under softmax+PV instead of being exposed at the next iteration's top.
// (The lgkmcnt(0) fence does not touch vmcnt -> prefetch stays in flight.)
// Everything else identical to passing R12.
// ---------------------------------------------------------------------------
__global__ __launch_bounds__(256)
void attn_mfma(const short* __restrict__ Qh, const short* __restrict__ Kh,
               const short* __restrict__ Vt, short* __restrict__ Oh,
               int S, int bpb) {
    __shared__ __align__(16) unsigned P2[4][2][16][36];   // 18432 B
    __shared__ __align__(16) float MB[2][64][24];         // 12288 B

    const int tid = threadIdx.x;
    const int w = tid >> 6, l = tid & 63;
    const int pw = w >> 1, half = w & 1;
    const int lo = l & 15, hi = l >> 4;
    const int T = S >> 4;

    // XCD-aware decode: flat = (bh&7) + 8*((bh>>3)*bpb + blk)
    const int flat = blockIdx.x;
    const int bh3 = flat & 7;
    const int r = flat >> 3;
    const int grp = r / bpb, blk = r - grp * bpb;
    const int bh = grp * 8 + bh3;
    const int b = bh >> 4, h = bh & 15;          // NH = 16
    const int p = blk * 2 + pw;

    const int q0B = (T - 1 - p) << 4;
    const int q0F = p << 4;
    const int nkbB = (q0B + 79) >> 6;
    const int nkbF = (q0F + 79) >> 6;

    const short* Qp = Qh + (size_t)bh * S * DH;
    const short* Kp = Kh + (size_t)bh * S * DH;
    const short* Vp = Vt + (size_t)bh * DH * S;

    const short8v qB0 = *(const short8v*)(Qp + (size_t)(q0B + lo) * DH + hi * 8);
    const short8v qB1 = *(const short8v*)(Qp + (size_t)(q0B + lo) * DH + 32 + hi * 8);
    const short8v qF0 = *(const short8v*)(Qp + (size_t)(q0F + lo) * DH + hi * 8);
    const short8v qF1 = *(const short8v*)(Qp + (size_t)(q0F + lo) * DH + 32 + hi * 8);

    short8v ones;
    #pragma unroll
    for (int i = 0; i < 8; ++i) ones[i] = (short)0x3F80;   // bf16 1.0

    f32x4 oB[4], oF[4];
    f32x4 laB = (f32x4){0.f, 0.f, 0.f, 0.f};
    f32x4 laF = (f32x4){0.f, 0.f, 0.f, 0.f};
    float mB = -INFINITY, mF = -INFINITY;   // per-lane running max (q = q0+lo)
    #pragma unroll
    for (int i = 0; i < 4; ++i) {
        oB[i] = (f32x4){0.f, 0.f, 0.f, 0.f};
        oF[i] = (f32x4){0.f, 0.f, 0.f, 0.f};
    }
    const f32x4 z = (f32x4){0.f, 0.f, 0.f, 0.f};

    // in-register softmax for one tile (swapped layout), then P2 store
    auto softmaxTile = [&](const f32x4 (&s)[4], float& m, f32x4 (&o)[4],
                           f32x4& la, bool masked, int q0, int kvb, int tsel) {
        float pv[16];
        float bm = -INFINITY;
        const int lim = q0 + lo - kvb;   // unmasked iff kt*16+hi*4+rg <= lim
        #pragma unroll
        for (int kt = 0; kt < 4; ++kt)
            #pragma unroll
            for (int rg = 0; rg < 4; ++rg) {
                float v = s[kt][rg];
                if (masked && (kt * 16 + hi * 4 + rg > lim)) v = -INFINITY;
                pv[kt * 4 + rg] = v;
                bm = fmaxf(bm, v);
            }
        bm = fmaxf(bm, __shfl_xor(bm, 16));
        bm = fmaxf(bm, __shfl_xor(bm, 32));
        if (__any(bm > m + 8.0f)) {
            const float mn = fmaxf(m, bm);
            const float c = __expf(m - mn);
            m = mn;
            #pragma unroll
            for (int rg = 0; rg < 4; ++rg) {
                const float cr = bperm_f(hi * 4 + rg, c);
                la[rg] *= cr;
                #pragma unroll
                for (int dt = 0; dt < 4; ++dt) o[dt][rg] *= cr;
            }
        }
        #pragma unroll
        for (int kt = 0; kt < 4; ++kt) {
            uint2 wv;
            wv.x = cvtpk(__expf(pv[kt * 4 + 0] - m), __expf(pv[kt * 4 + 1] - m));
            wv.y = cvtpk(__expf(pv[kt * 4 + 2] - m), __expf(pv[kt * 4 + 3] - m));
            *(uint2*)&P2[w][tsel][lo][kt * 8 + hi * 2] = wv;
        }
    };

    short8v kfA0[4], kfA1[4], kfB0[4], kfB1[4];

#define LOAD_K(KB, KF0, KF1)                                               \
    do {                                                                   \
        const int kvn = (KB) * 64;                                         \
        _Pragma("unroll")                                                  \
        for (int kt = 0; kt < 4; ++kt) {                                   \
            const short* kbase = Kp + (size_t)(kvn + kt * 16 + lo) * DH + hi * 8; \
            KF0[kt] = *(const short8v*)(kbase);                            \
            KF1[kt] = *(const short8v*)(kbase + 32);                       \
        }                                                                  \
    } while (0)

#define ATTN_ITER(KB, CKF0, CKF1, NKF0, NKF1)                              \
    do {                                                                   \
        const int kvb = (KB) * 64;                                         \
        const bool actF = (KB) < nkbF;                                     \
        short8v vf0[4], vf1[4];                                            \
        _Pragma("unroll")                                                  \
        for (int dt = 0; dt < 4; ++dt) {                                   \
            const short* vbase = Vp + (size_t)(dt * 16 + lo) * S + kvb + hi * 8; \
            vf0[dt] = *(const short8v*)(vbase);                            \
            vf1[dt] = *(const short8v*)(vbase + 32);                       \
        }                                                                  \
        f32x4 sB[4], sF[4];                                                \
        _Pragma("unroll")                                                  \
        for (int kt = 0; kt < 4; ++kt) {                                   \
            f32x4 a = z;                                                   \
            a = __builtin_amdgcn_mfma_f32_16x16x32_bf16(CKF0[kt], qB0, a, 0, 0, 0); \
            a = __builtin_amdgcn_mfma_f32_16x16x32_bf16(CKF1[kt], qB1, a, 0, 0, 0); \
            sB[kt] = a;                                                    \
        }                                                                  \
        if (actF) {                                                        \
            _Pragma("unroll")                                              \
            for (int kt = 0; kt < 4; ++kt) {                               \
                f32x4 a = z;                                               \
                a = __builtin_amdgcn_mfma_f32_16x16x32_bf16(CKF0[kt], qF0, a, 0, 0, 0); \
                a = __builtin_amdgcn_mfma_f32_16x16x32_bf16(CKF1[kt], qF1, a, 0, 0, 0); \
                sF[kt] = a;                                                \
            }                                                              \
        }                                                                  \
        if ((KB) + 2 < nkbB) LOAD_K((KB) + 2, NKF0, NKF1);                 \
        softmaxTile(sB, mB, oB, laB, (KB) == nkbB - 1, q0B, kvb, 0);       \
        if (actF) softmaxTile(sF, mF, oF, laF, (KB) == nkbF - 1, q0F, kvb, 1); \
        asm volatile("s_waitcnt lgkmcnt(0)" ::: "memory");                 \
        {                                                                  \
            const short8v paB0 = *(const short8v*)&P2[w][0][lo][hi * 4];   \
            const short8v paB1 = *(const short8v*)&P2[w][0][lo][16 + hi * 4]; \
            laB = __builtin_amdgcn_mfma_f32_16x16x32_bf16(paB0, ones, laB, 0, 0, 0); \
            laB = __builtin_amdgcn_mfma_f32_16x16x32_bf16(paB1, ones, laB, 0, 0, 0); \
            _Pragma("unroll")                                              \
            for (int dt = 0; dt < 4; ++dt) {                               \
                oB[dt] = __builtin_amdgcn_mfma_f32_16x16x32_bf16(paB0, vf0[dt], oB[dt], 0, 0, 0); \
                oB[dt] = __builtin_amdgcn_mfma_f32_16x16x32_bf16(paB1, vf1[dt], oB[dt], 0, 0, 0); \
            }                                                              \
            if (actF) {                                                    \
                const short8v paF0 = *(const short8v*)&P2[w][1][lo][hi * 4]; \
                const short8v paF1 = *(const short8v*)&P2[w][1][lo][16 + hi * 4]; \
                laF = __builtin_amdgcn_mfma_f32_16x16x32_bf16(paF0, ones, laF, 0, 0, 0); \
                laF = __builtin_amdgcn_mfma_f32_16x16x32_bf16(paF1, ones, laF, 0, 0, 0); \
                _Pragma("unroll")                                          \
                for (int dt = 0; dt < 4; ++dt) {                           \
                    oF[dt] = __builtin_amdgcn_mfma_f32_16x16x32_bf16(paF0, vf0[dt], oF[dt], 0, 0, 0); \
                    oF[dt] = __builtin_amdgcn_mfma_f32_16x16x32_bf16(paF1, vf1[dt], oF[dt], 0, 0, 0); \
                }                                                          \
            }                                                              \
        }                                                                  \
    } while (0)

    int kb = half;
    if (kb < nkbB) LOAD_K(kb, kfA0, kfA1);
    while (kb < nkbB) {
        ATTN_ITER(kb, kfA0, kfA1, kfB0, kfB1);
        kb += 2;
        if (kb >= nkbB) break;
        ATTN_ITER(kb, kfB0, kfB1, kfA0, kfA1);
        kb += 2;
    }
#undef ATTN_ITER
#undef LOAD_K

    // ---- m (per-lane, q=lo) -> row layout for the merge
    float mBr[4], mFr[4];
    #pragma unroll
    for (int rg = 0; rg < 4; ++rg) {
        mBr[rg] = bperm_f(hi * 4 + rg, mB);
        mFr[rg] = bperm_f(hi * 4 + rg, mF);
    }

    // ---- KV-split combine (identical structure to R12, spill-free) ----
#define STORE_TILE(OT, MT, LAT)                                            \
    do {                                                                   \
        f32x4* dst = (f32x4*)&MB[pw][l][0];                                \
        dst[0] = OT[0]; dst[1] = OT[1]; dst[2] = OT[2]; dst[3] = OT[3];    \
        dst[4] = (f32x4){MT[0], MT[1], MT[2], MT[3]};                      \
        dst[5] = LAT;                                                      \
    } while (0)

#define MERGE_TILE(OT, MT, LAT, Q0T)                                       \
    do {                                                                   \
        const f32x4* src = (const f32x4*)&MB[pw][l][0];                    \
        const f32x4 o1_0 = src[0], o1_1 = src[1], o1_2 = src[2], o1_3 = src[3]; \
        const f32x4 m1 = src[4];                                           \
        const f32x4 la1 = src[5];                                          \
        short* Op = Oh + (size_t)(b * S + (Q0T)) * DM + h * DH;            \
        _Pragma("unroll")                                                  \
        for (int rg = 0; rg < 4; ++rg) {                                   \
            const float mst = fmaxf(MT[rg], m1[rg]);                       \
            const float c0 = __expf(MT[rg] - mst);                         \
            const float c1 = __expf(m1[rg] - mst);                         \
            const float iv = 1.0f / (LAT[rg] * c0 + la1[rg] * c1);         \
            Op[(size_t)(hi * 4 + rg) * DM +  0 + lo] = f2bf((OT[0][rg] * c0 + o1_0[rg] * c1) * iv); \
            Op[(size_t)(hi * 4 + rg) * DM + 16 + lo] = f2bf((OT[1][rg] * c0 + o1_1[rg] * c1) * iv); \
            Op[(size_t)(hi * 4 + rg) * DM + 32 + lo] = f2bf((OT[2][rg] * c0 + o1_2[rg] * c1) * iv); \
            Op[(size_t)(hi * 4 + rg) * DM + 48 + lo] = f2bf((OT[3][rg] * c0 + o1_3[rg] * c1) * iv); \
        }                                                                  \
    } while (0)

    __syncthreads();
    if (half == 1) STORE_TILE(oB, mBr, laB);
    __syncthreads();
    if (half == 0) MERGE_TILE(oB, mBr, laB, q0B);
    __syncthreads();
    if (half == 1) STORE_TILE(oF, mFr, laF);
    __syncthreads();
    if (half == 0) MERGE_TILE(oF, mFr, laF, q0F);
#undef STORE_TILE
#undef MERGE_TILE
}

// ---------------------------------------------------------------------------
extern "C" void kernel_launch(void* const* d_in, const int* in_sizes, int n_in,
                              void* d_out, int out_size, void* d_ws, size_t ws_size,
                              hipStream_t stream) {
    const float* x  = (const float*)d_in[0];
    const int*  pos = (const int*)d_in[1];
    const float* wq = (const float*)d_in[2];
    const float* wk = (const float*)d_in[3];
    const float* wv = (const float*)d_in[4];
    const float* wo = (const float*)d_in[5];
    float* out = (float*)d_out;

    const int S = in_sizes[1];              // 2048
    const int rows = in_sizes[0] / DM;      // B*S
    const int Bb = rows / S;

    short* xh   = (short*)d_ws;
    short* wqkv = xh + (size_t)rows * DM;
    short* woh  = wqkv + (size_t)QKV * DM;
    short* QKVr = woh + (size_t)DM * DM;
    short* Qh   = QKVr + (size_t)rows * QKV;
    short* Kh   = Qh + (size_t)rows * DM;
    short* Vt   = Kh + (size_t)rows * DM;
    short* Oh   = Vt + (size_t)rows * DM;
    // cos/sin table overlays the xh region (dead after the QKV GEMM).
    float2* cst = (float2*)xh;

    const int nx = rows * DM;
    const int nw = DM * DM;
    const int ntot = nx + 4 * nw;
    convert_inputs<<<(ntot / 4 + 255) / 256, 256, 0, stream>>>(
        x, wq, wk, wv, wo, xh, wqkv, woh, nx, nw);

    gemm_bt_mfma<1><<<dim3(QKV / 128, rows / 128), 256, 0, stream>>>(
        xh, wqkv, QKVr, rows, QKV, DM);

    build_cs<<<(S * 32 + 255) / 256, 256, 0, stream>>>(pos, cst, S);

    const int total = 2 * rows * (DM / 2);
    rope_bf16<<<(total + 255) / 256, 256, 0, stream>>>(QKVr, cst, Qh, Kh, S, rows);
    v_transpose_bf16<<<dim3(S / 64, Bb * NH), 256, 0, stream>>>(QKVr, Vt, S);

    // XCD-swizzled 1D grid: nbh * bpb blocks, flat%8 selects bh%8.
    const int Tq = S / 16;
    const int bpb = Tq / 4;                 // blocks per (b,h): 2 pairs/block
    const int nbh = Bb * NH;
    attn_mfma<<<dim3(nbh * bpb), 256, 0, stream>>>(Qh, Kh, Vt, Oh, S, bpb);

    gemm_bt_mfma<0><<<dim3(DM / 128, rows / 128), 256, 0, stream>>>(
        Oh, woh, out, rows, DM, DM);
}